// Round 1
// baseline (607.974 us; speedup 1.0000x reference)
//
#include <hip/hip_runtime.h>
#include <hip/hip_bf16.h>

typedef unsigned short u16;
typedef __attribute__((ext_vector_type(8))) short short8;
typedef __attribute__((ext_vector_type(4))) short short4v;
typedef __attribute__((ext_vector_type(4))) float f32x4;

#define NEGV -1000000000000000.0f

__device__ __forceinline__ u16 f2bf(float f) {
  unsigned u = __float_as_uint(f);
  unsigned r = (u + 0x7FFFu + ((u >> 16) & 1u)) >> 16;
  return (u16)r;
}
__device__ __forceinline__ float bf2f(u16 s) {
  return __uint_as_float(((unsigned)s) << 16);
}
__device__ __forceinline__ void lds16(const void* g, void* l) {
  __builtin_amdgcn_global_load_lds((const __attribute__((address_space(1))) void*)g,
                                   (__attribute__((address_space(3))) void*)l,
                                   16, 0, 0);
}

// ---------------- generic bf16 GEMM, C = A(MxK) * B(NxK)^T, 128x128 tile ----
// EPI: 0 = fp32 + row/col bias (S), 1 = bf16 store, 2 = bf16 transposed store,
//      3 = fp32 store
template <int EPI>
__global__ __launch_bounds__(256) void gemm_bt(
    const u16* __restrict__ A, long long sA, int lda,
    const u16* __restrict__ B, long long sB, int ldb,
    void* __restrict__ Cv, long long sC, int ldc, int K,
    const float* __restrict__ brow, const float* __restrict__ bcol,
    int brs, int bcs) {
  __shared__ u16 As[128 * 64];
  __shared__ u16 Bs[128 * 64];
  const int b = blockIdx.z;
  const int m0 = blockIdx.x * 128;
  const int n0 = blockIdx.y * 128;
  const u16* Ab = A + (size_t)b * sA;
  const u16* Bb = B + (size_t)b * sB;
  const int t = threadIdx.x;
  const int lane = t & 63;
  const int w = t >> 6;
  const int wr = w >> 1, wc = w & 1;
  const int srow = lane >> 3;
  const int scol = (lane & 7) * 8;

  f32x4 acc[4][4] = {};

  for (int k0 = 0; k0 < K; k0 += 64) {
    __syncthreads();
#pragma unroll
    for (int qq = 0; qq < 4; ++qq) {
      const int q = w * 4 + qq;
      const int r = q * 8 + srow;
      lds16(Ab + (size_t)(m0 + r) * lda + k0 + scol, &As[q * 512]);
      lds16(Bb + (size_t)(n0 + r) * ldb + k0 + scol, &Bs[q * 512]);
    }
    __syncthreads();
#pragma unroll
    for (int ks = 0; ks < 2; ++ks) {
      short8 af[4], bg[4];
      const int fro = lane & 15;
      const int k8 = ks * 32 + (lane >> 4) * 8;
#pragma unroll
      for (int i = 0; i < 4; ++i)
        af[i] = *(const short8*)&As[(wr * 64 + i * 16 + fro) * 64 + k8];
#pragma unroll
      for (int i = 0; i < 4; ++i)
        bg[i] = *(const short8*)&Bs[(wc * 64 + i * 16 + fro) * 64 + k8];
#pragma unroll
      for (int i = 0; i < 4; ++i)
#pragma unroll
        for (int j = 0; j < 4; ++j)
          acc[i][j] =
              __builtin_amdgcn_mfma_f32_16x16x32_bf16(af[i], bg[j], acc[i][j], 0, 0, 0);
    }
  }

  const int col = lane & 15;
  const int r4 = (lane >> 4) * 4;
#pragma unroll
  for (int i = 0; i < 4; ++i) {
#pragma unroll
    for (int j = 0; j < 4; ++j) {
      const int cc = n0 + wc * 64 + j * 16 + col;
#pragma unroll
      for (int g = 0; g < 4; ++g) {
        const int rr = m0 + wr * 64 + i * 16 + r4 + g;
        float v = acc[i][j][g];
        if (EPI == 0) {
          v += brow[b * brs + rr] + bcol[b * bcs + cc];
          ((float*)Cv)[(size_t)b * sC + (size_t)rr * ldc + cc] = v;
        } else if (EPI == 1) {
          ((u16*)Cv)[(size_t)b * sC + (size_t)rr * ldc + cc] = f2bf(v);
        } else if (EPI == 2) {
          ((u16*)Cv)[(size_t)b * sC + (size_t)cc * ldc + rr] = f2bf(v);
        } else {
          ((float*)Cv)[(size_t)b * sC + (size_t)rr * ldc + cc] = v;
        }
      }
    }
  }
}

// ---- prep: C (B,512,1024) fp32 -> O chunk0 = C_t bf16 (ld 2048), Corig bf16 -
__global__ __launch_bounds__(256) void prep_C(const float* __restrict__ C,
                                              u16* __restrict__ O,
                                              u16* __restrict__ Corig) {
  __shared__ float L[64][65];
  const int b = blockIdx.z;
  const int d0 = blockIdx.y * 64;
  const int i0 = blockIdx.x * 64;
  const int t = threadIdx.x;
  const int cx = t & 63;
  const int rb = t >> 6;
  const float* Cb = C + ((size_t)b * 512 + d0) * 1024 + i0;
#pragma unroll
  for (int rr = 0; rr < 16; ++rr) {
    const int r = rb * 16 + rr;
    const float v = Cb[(size_t)r * 1024 + cx];
    L[r][cx] = v;
    Corig[((size_t)b * 512 + d0 + r) * 1024 + i0 + cx] = f2bf(v);
  }
  __syncthreads();
#pragma unroll
  for (int rr = 0; rr < 16; ++rr) {
    const int il = rb * 16 + rr;
    O[((size_t)b * 1024 + i0 + il) * 2048 + d0 + cx] = f2bf(L[cx][il]);
  }
}

// ---- prep: Q (B,512,128) -> Qmb = (Q_t * w_m) bf16 (128x512), Qorig bf16 ----
__global__ __launch_bounds__(256) void prep_Q(const float* __restrict__ Q,
                                              const float* __restrict__ W0,
                                              u16* __restrict__ Qmb,
                                              u16* __restrict__ Qorig) {
  __shared__ float L[64][65];
  const int b = blockIdx.z;
  const int d0 = blockIdx.y * 64;
  const int j0 = blockIdx.x * 64;
  const int t = threadIdx.x;
  const int cx = t & 63;
  const int rb = t >> 6;
  const float* Qb = Q + ((size_t)b * 512 + d0) * 128 + j0;
#pragma unroll
  for (int rr = 0; rr < 16; ++rr) {
    const int r = rb * 16 + rr;
    const float v = Qb[(size_t)r * 128 + cx];
    L[r][cx] = v;
    Qorig[((size_t)b * 512 + d0 + r) * 128 + j0 + cx] = f2bf(v);
  }
  __syncthreads();
  const float wm = W0[1024 + d0 + cx];
#pragma unroll
  for (int rr = 0; rr < 16; ++rr) {
    const int jl = rb * 16 + rr;
    Qmb[((size_t)b * 128 + j0 + jl) * 512 + d0 + cx] = f2bf(L[cx][jl] * wm);
  }
}

// ---- biases: cbias[b,i] = sum_d C[b,d,i]*w_c[d]; qbias likewise ------------
__global__ __launch_bounds__(256) void bias_c(const float* __restrict__ C,
                                              const float* __restrict__ W0,
                                              float* __restrict__ cb) {
  const int b = blockIdx.y;
  const int i = blockIdx.x * 256 + threadIdx.x;
  const float* Cb = C + (size_t)b * 524288;
  float a = 0.f;
  for (int d = 0; d < 512; ++d) a = fmaf(Cb[(size_t)d * 1024 + i], W0[d], a);
  cb[b * 1024 + i] = a;
}

__global__ __launch_bounds__(128) void bias_q(const float* __restrict__ Q,
                                              const float* __restrict__ W0,
                                              float* __restrict__ qb) {
  const int b = blockIdx.x;
  const int j = threadIdx.x;
  const float* Qb = Q + (size_t)b * 65536;
  float a = 0.f;
  for (int d = 0; d < 512; ++d) a = fmaf(Qb[(size_t)d * 128 + j], W0[512 + d], a);
  qb[b * 128 + j] = a;
}

// ---- row softmax over j (width 128), one wave per row ----------------------
__global__ __launch_bounds__(256) void row_softmax(const float* __restrict__ S,
                                                   const float* __restrict__ qmask,
                                                   u16* __restrict__ Sbar) {
  const int t = threadIdx.x;
  const int lane = t & 63;
  const int row = blockIdx.x * 4 + (t >> 6);
  const int b = row >> 10;
  const float* Sr = S + (size_t)row * 128;
  const float* qmb = qmask + b * 128;
  const int j0 = lane * 2;
  const float q0 = qmb[j0], q1 = qmb[j0 + 1];
  const float x0 = Sr[j0] * q0 + NEGV * (1.f - q0);
  const float x1 = Sr[j0 + 1] * q1 + NEGV * (1.f - q1);
  float mx = fmaxf(x0, x1);
  for (int o = 32; o; o >>= 1) mx = fmaxf(mx, __shfl_xor(mx, o));
  const float e0 = expf(x0 - mx), e1 = expf(x1 - mx);
  float s = e0 + e1;
  for (int o = 32; o; o >>= 1) s += __shfl_xor(s, o);
  const float inv = 1.f / s;
  unsigned pack = (unsigned)f2bf(e0 * inv) | ((unsigned)f2bf(e1 * inv) << 16);
  *(unsigned*)(Sbar + (size_t)row * 128 + j0) = pack;
}

// ---- column stats (max, sumexp) per (b, j) ---------------------------------
__global__ __launch_bounds__(1024) void col_stats(const float* __restrict__ S,
                                                  const float* __restrict__ cmask,
                                                  float* __restrict__ cmx,
                                                  float* __restrict__ csm) {
  __shared__ float sm[8][128];
  __shared__ float sl[8][128];
  const int b = blockIdx.x;
  const int t = threadIdx.x;
  const int j = t & 127, g = t >> 7;
  const float* Sb = S + (size_t)b * 131072;
  const float* cm = cmask + b * 1024;
  float m = -3.4e38f;
  for (int ii = 0; ii < 128; ++ii) {
    const int i = g * 128 + ii;
    const float c = cm[i];
    m = fmaxf(m, Sb[(size_t)i * 128 + j] * c + NEGV * (1.f - c));
  }
  sm[g][j] = m;
  __syncthreads();
  if (g == 0) {
    float M = sm[0][j];
#pragma unroll
    for (int k = 1; k < 8; ++k) M = fmaxf(M, sm[k][j]);
    sm[0][j] = M;
  }
  __syncthreads();
  const float M = sm[0][j];
  float l = 0.f;
  for (int ii = 0; ii < 128; ++ii) {
    const int i = g * 128 + ii;
    const float c = cm[i];
    l += expf(Sb[(size_t)i * 128 + j] * c + NEGV * (1.f - c) - M);
  }
  sl[g][j] = l;
  __syncthreads();
  if (g == 0) {
    float L = 0.f;
#pragma unroll
    for (int k = 0; k < 8; ++k) L += sl[k][j];
    cmx[b * 128 + j] = M;
    csm[b * 128 + j] = L;
  }
}

// ---- S_bbar^T (B,128,1024) bf16, via LDS transpose -------------------------
__global__ __launch_bounds__(256) void sbbt_k(const float* __restrict__ S,
                                              const float* __restrict__ cmask,
                                              const float* __restrict__ cmx,
                                              const float* __restrict__ csm,
                                              u16* __restrict__ Sbbt) {
  __shared__ u16 L[128][130];
  const int b = blockIdx.y;
  const int i0 = blockIdx.x * 128;
  const int t = threadIdx.x;
  const int j = t & 127, ih = t >> 7;
  const float* Sb = S + (size_t)b * 131072;
  const float* cm = cmask + b * 1024;
  const float M = cmx[b * 128 + j];
  const float R = 1.f / csm[b * 128 + j];
  for (int ii = 0; ii < 64; ++ii) {
    const int il = ih * 64 + ii;
    const float c = cm[i0 + il];
    const float x = Sb[(size_t)(i0 + il) * 128 + j] * c + NEGV * (1.f - c);
    L[il][j] = f2bf(expf(x - M) * R);
  }
  __syncthreads();
  const int ip = t & 127, jb = t >> 7;
  for (int jj = 0; jj < 64; ++jj) {
    const int jl = jb * 64 + jj;
    Sbbt[((size_t)b * 128 + jl) * 1024 + i0 + ip] = L[ip][jl];
  }
}

// ---- O3 = O1*O2, O4 = O1*O4 (bf16 elementwise) -----------------------------
__global__ __launch_bounds__(256) void products(u16* __restrict__ O) {
  const size_t nvec = 4194304;  // 64*1024*512/8
  for (size_t v = (size_t)blockIdx.x * 256 + threadIdx.x; v < nvec;
       v += (size_t)gridDim.x * 256) {
    const size_t f = v * 8;
    const size_t bc = f >> 9;
    const int dd = (int)(f & 511);
    u16* base = O + bc * 2048 + dd;
    short8 c8 = *(short8*)(base);
    short8 a8 = *(short8*)(base + 512);
    short8 b8 = *(short8*)(base + 1536);
    short8 p3, p4;
#pragma unroll
    for (int k = 0; k < 8; ++k) {
      const float cf = bf2f((u16)c8[k]);
      p3[k] = (short)f2bf(cf * bf2f((u16)a8[k]));
      p4[k] = (short)f2bf(cf * bf2f((u16)b8[k]));
    }
    *(short8*)(base + 1024) = p3;
    *(short8*)(base + 1536) = p4;
  }
}

// ---- Wr fp32 -> bf16 -------------------------------------------------------
__global__ __launch_bounds__(256) void cvt_wr(const float* __restrict__ Wr,
                                              u16* __restrict__ Wrb) {
  const int idx = blockIdx.x * 256 + threadIdx.x;
  const float4 v = ((const float4*)Wr)[idx];
  short4v o;
  o[0] = (short)f2bf(v.x);
  o[1] = (short)f2bf(v.y);
  o[2] = (short)f2bf(v.z);
  o[3] = (short)f2bf(v.w);
  *(short4v*)&Wrb[(size_t)idx * 4] = o;
}

extern "C" void kernel_launch(void* const* d_in, const int* in_sizes, int n_in,
                              void* d_out, int out_size, void* d_ws, size_t ws_size,
                              hipStream_t stream) {
  (void)in_sizes; (void)n_in; (void)out_size;
  const float* C = (const float*)d_in[0];
  const float* Q = (const float*)d_in[1];
  const float* cm = (const float*)d_in[2];
  const float* qm = (const float*)d_in[3];
  const float* W0 = (const float*)d_in[4];
  const float* Wr = (const float*)d_in[5];
  float* out = (float*)d_out;

  if (ws_size < 430276608ull) return;  // need ~410 MiB scratch

  char* p = (char*)d_ws;
  u16* O     = (u16*)(p);                    // (B,1024,2048) bf16: [C_t|A|C*A|C*Bm]
  u16* Corig = (u16*)(p + 268435456ull);     // (B,512,1024) bf16
  u16* Qmb   = (u16*)(p + 335544320ull);     // (B,128,512)  bf16  Q_t*w_m
  u16* Qorig = (u16*)(p + 343932928ull);     // (B,512,128)  bf16
  float* S   = (float*)(p + 352321536ull);   // (B,1024,128) fp32
  u16* Sbar  = (u16*)(p + 385875968ull);     // (B,1024,128) bf16
  u16* Sbbt  = (u16*)(p + 402653184ull);     // (B,128,1024) bf16
  u16* Tt    = (u16*)(p + 419430400ull);     // (B,512,128)  bf16  T^T
  u16* Wrb   = (u16*)(p + 427819008ull);     // (512,2048)   bf16
  float* cb  = (float*)(p + 429916160ull);   // (B,1024)
  float* qb  = (float*)(p + 430178304ull);   // (B,128)
  float* cmx = (float*)(p + 430211072ull);   // (B,128)
  float* csm = (float*)(p + 430243840ull);   // (B,128)

  cvt_wr<<<dim3(1024), dim3(256), 0, stream>>>(Wr, Wrb);
  prep_C<<<dim3(16, 8, 64), dim3(256), 0, stream>>>(C, O, Corig);
  prep_Q<<<dim3(2, 8, 64), dim3(256), 0, stream>>>(Q, W0, Qmb, Qorig);
  bias_c<<<dim3(4, 64), dim3(256), 0, stream>>>(C, W0, cb);
  bias_q<<<dim3(64), dim3(128), 0, stream>>>(Q, W0, qb);

  // S = C_t @ (Q_t*w_m)^T + cbias + qbias   (M=1024,N=128,K=512)
  gemm_bt<0><<<dim3(8, 1, 64), dim3(256), 0, stream>>>(
      O, 2097152ll, 2048, Qmb, 65536ll, 512, S, 131072ll, 128, 512, cb, qb, 1024, 128);

  row_softmax<<<dim3(16384), dim3(256), 0, stream>>>(S, qm, Sbar);
  col_stats<<<dim3(64), dim3(1024), 0, stream>>>(S, cm, cmx, csm);
  sbbt_k<<<dim3(8, 64), dim3(256), 0, stream>>>(S, cm, cmx, csm, Sbbt);

  // A = Sbar @ Q_t  (M=1024,N=512,K=128) -> O chunk 1
  gemm_bt<1><<<dim3(8, 4, 64), dim3(256), 0, stream>>>(
      Sbar, 131072ll, 128, Qorig, 65536ll, 128, O + 512, 2097152ll, 2048, 128,
      nullptr, nullptr, 0, 0);
  // T^T: T = Sbbar^T @ C_t (M=128,N=512,K=1024), stored transposed (512x128)
  gemm_bt<2><<<dim3(1, 4, 64), dim3(256), 0, stream>>>(
      Sbbt, 131072ll, 1024, Corig, 524288ll, 1024, Tt, 65536ll, 128, 1024,
      nullptr, nullptr, 0, 0);
  // Bm = Sbar @ T (M=1024,N=512,K=128) -> O chunk 3
  gemm_bt<1><<<dim3(8, 4, 64), dim3(256), 0, stream>>>(
      Sbar, 131072ll, 128, Tt, 65536ll, 128, O + 1536, 2097152ll, 2048, 128,
      nullptr, nullptr, 0, 0);

  products<<<dim3(2048), dim3(256), 0, stream>>>(O);

  // R = Wr @ out^T  (M=512,N=1024,K=2048) per batch
  gemm_bt<3><<<dim3(4, 8, 64), dim3(256), 0, stream>>>(
      Wrb, 0ll, 2048, O, 2097152ll, 2048, out, 524288ll, 1024, 2048,
      nullptr, nullptr, 0, 0);
}

// Round 2
// 483.625 us; speedup vs baseline: 1.2571x; 1.2571x over previous
//
#include <hip/hip_runtime.h>
#include <hip/hip_bf16.h>

typedef unsigned short u16;
typedef __attribute__((ext_vector_type(8))) short short8;
typedef __attribute__((ext_vector_type(4))) short short4v;
typedef __attribute__((ext_vector_type(4))) float f32x4;

#define NEGV -1000000000000000.0f
#define SBAR() asm volatile("s_barrier" ::: "memory")

__device__ __forceinline__ u16 f2bf(float f) {
  unsigned u = __float_as_uint(f);
  unsigned r = (u + 0x7FFFu + ((u >> 16) & 1u)) >> 16;
  return (u16)r;
}
__device__ __forceinline__ float bf2f(u16 s) {
  return __uint_as_float(((unsigned)s) << 16);
}
__device__ __forceinline__ void lds16(const void* g, void* l) {
  __builtin_amdgcn_global_load_lds((const __attribute__((address_space(1))) void*)g,
                                   (__attribute__((address_space(3))) void*)l,
                                   16, 0, 0);
}

// ============ 256x256 8-phase GEMM: out = Wrb(512x2048) @ Oflat(65536x2048)^T
// T2 swizzle (pre-swizzled global source, swizzled ds_read), T3+T4 counted
// vmcnt (6/4, never 0), T5 setprio, raw s_barrier. 8 waves (2M x 4N), BK=64.
__global__ __launch_bounds__(512, 2) void gemm8(const u16* __restrict__ A,
                                                const u16* __restrict__ B,
                                                float* __restrict__ out) {
  extern __shared__ u16 lds[];  // 128 KiB: A dbuf [2][256][64] | B dbuf [2][256][64]
  const int bid = blockIdx.x;
  const int wg = (bid & 7) * 64 + (bid >> 3);  // pair (2p,2p+1) same XCD, shared B-tile
  const int m0 = (wg & 1) * 256;
  const int n0 = (wg >> 1) * 256;
  const int tid = threadIdx.x;
  const int lane = tid & 63;
  const int w = tid >> 6;
  const int wr = w >> 2;
  const int wc = w & 3;
  const int fro = lane & 15;
  const int hi = lane >> 4;
  const int kx = fro & 7;
  const int sr = lane >> 3;
  const int sgc = ((lane & 7) ^ sr) << 3;  // pre-swizzled source column (elems)

  const u16* Ag = A + (size_t)m0 * 2048;
  const u16* Bg = B + (size_t)n0 * 2048;

  const int rA = wr * 128 + fro;  // + i*16
  const int rB = wc * 64 + fro;   // + j*16

  f32x4 acc[8][4] = {};
  short8 aX[4][2], aY[4][2], bP[2][2], bQ[2][2];

#define STG2(gp, lp)                                                          \
  {                                                                           \
    lds16((gp) + (size_t)((w * 2 + 0) * 8 + sr) * 2048 + sgc,                 \
          (u16*)(lp) + (w * 2 + 0) * 512);                                    \
    lds16((gp) + (size_t)((w * 2 + 1) * 8 + sr) * 2048 + sgc,                 \
          (u16*)(lp) + (w * 2 + 1) * 512);                                    \
  }
#define RDF(base, row, k16) \
  (*(const short8*)&(base)[(size_t)(row) * 64 + (((k16) ^ kx) << 3)])

  // ---- prologue: tile0 (4 halves -> buf0), A halves of tile1 -> buf1
  STG2(Ag, lds);                        // A-low  t0
  STG2(Ag + 262144, lds + 8192);        // A-high t0
  STG2(Bg, lds + 32768);                // B-low  t0
  STG2(Bg + 262144, lds + 40960);       // B-high t0
  STG2(Ag + 64, lds + 16384);           // A-low  t1
  STG2(Ag + 262144 + 64, lds + 24576);  // A-high t1
  asm volatile("s_waitcnt vmcnt(4)" ::: "memory");  // tile0 complete
  SBAR();
#pragma unroll
  for (int i = 0; i < 4; ++i)
#pragma unroll
    for (int ks = 0; ks < 2; ++ks) aX[i][ks] = RDF(lds, rA + i * 16, ks * 4 + hi);

  for (int t = 0; t < 32; ++t) {
    const int cur = t & 1;
    const int nxt = cur ^ 1;
    const u16* LA = lds + cur * 16384;
    const u16* LB = lds + 32768 + cur * 16384;
    u16* LBs = lds + 32768 + nxt * 16384;  // stage B(t+1)
    u16* LAs = lds + cur * 16384;          // stage A(t+2)
    const u16* LAn = lds + nxt * 16384;
    const int kk1 = (t < 31 ? t + 1 : 31) * 64;
    const int kk2 = (t < 30 ? t + 2 : 31) * 64;

    // ---- phase 0: read bP(t); stage B-low(t+1); mfma q0 = i0-3 x j0-1
#pragma unroll
    for (int j = 0; j < 2; ++j)
#pragma unroll
      for (int ks = 0; ks < 2; ++ks) bP[j][ks] = RDF(LB, rB + j * 16, ks * 4 + hi);
    STG2(Bg + kk1, LBs);
    SBAR();
    __builtin_amdgcn_s_setprio(1);
#pragma unroll
    for (int i = 0; i < 4; ++i)
#pragma unroll
      for (int j = 0; j < 2; ++j)
#pragma unroll
        for (int ks = 0; ks < 2; ++ks)
          acc[i][j] = __builtin_amdgcn_mfma_f32_16x16x32_bf16(aX[i][ks], bP[j][ks],
                                                              acc[i][j], 0, 0, 0);
    __builtin_amdgcn_s_setprio(0);
    SBAR();

    // ---- phase 1: read bQ(t), aY(t); stage B-high(t+1); mfma q1 = i0-3 x j2-3
#pragma unroll
    for (int j = 0; j < 2; ++j)
#pragma unroll
      for (int ks = 0; ks < 2; ++ks)
        bQ[j][ks] = RDF(LB, rB + (j + 2) * 16, ks * 4 + hi);
#pragma unroll
    for (int i = 0; i < 4; ++i)
#pragma unroll
      for (int ks = 0; ks < 2; ++ks)
        aY[i][ks] = RDF(LA, rA + (i + 4) * 16, ks * 4 + hi);
    STG2(Bg + 262144 + kk1, LBs + 8192);
    SBAR();
    __builtin_amdgcn_s_setprio(1);
#pragma unroll
    for (int i = 0; i < 4; ++i)
#pragma unroll
      for (int j = 0; j < 2; ++j)
#pragma unroll
        for (int ks = 0; ks < 2; ++ks)
          acc[i][j + 2] = __builtin_amdgcn_mfma_f32_16x16x32_bf16(
              aX[i][ks], bQ[j][ks], acc[i][j + 2], 0, 0, 0);
    __builtin_amdgcn_s_setprio(0);
    SBAR();

    // ---- phase 2: stage A-low(t+2); vmcnt(6) -> A(t+1) done; mfma q2 = i4-7 x j2-3
    STG2(Ag + kk2, LAs);
    asm volatile("s_waitcnt vmcnt(6)" ::: "memory");
    SBAR();
    __builtin_amdgcn_s_setprio(1);
#pragma unroll
    for (int i = 0; i < 4; ++i)
#pragma unroll
      for (int j = 0; j < 2; ++j)
#pragma unroll
        for (int ks = 0; ks < 2; ++ks)
          acc[i + 4][j + 2] = __builtin_amdgcn_mfma_f32_16x16x32_bf16(
              aY[i][ks], bQ[j][ks], acc[i + 4][j + 2], 0, 0, 0);
    __builtin_amdgcn_s_setprio(0);
    SBAR();

    // ---- phase 3: read aX(t+1); stage A-high(t+2); vmcnt(4) -> B(t+1) done;
    //      mfma q3 = i4-7 x j0-1
#pragma unroll
    for (int i = 0; i < 4; ++i)
#pragma unroll
      for (int ks = 0; ks < 2; ++ks)
        aX[i][ks] = RDF(LAn, rA + i * 16, ks * 4 + hi);
    STG2(Ag + 262144 + kk2, LAs + 8192);
    asm volatile("s_waitcnt vmcnt(4)" ::: "memory");
    SBAR();
    __builtin_amdgcn_s_setprio(1);
#pragma unroll
    for (int i = 0; i < 4; ++i)
#pragma unroll
      for (int j = 0; j < 2; ++j)
#pragma unroll
        for (int ks = 0; ks < 2; ++ks)
          acc[i + 4][j] = __builtin_amdgcn_mfma_f32_16x16x32_bf16(
              aY[i][ks], bP[j][ks], acc[i + 4][j], 0, 0, 0);
    __builtin_amdgcn_s_setprio(0);
    SBAR();
  }
  asm volatile("s_waitcnt vmcnt(0)" ::: "memory");

  // ---- epilogue: out[b][r][c], n = n0 + wc*64 + j*16 + fro, b=n>>10, c=n&1023
  const int crow = m0 + wr * 128 + hi * 4;
#pragma unroll
  for (int i = 0; i < 8; ++i)
#pragma unroll
    for (int j = 0; j < 4; ++j) {
      const int n = n0 + wc * 64 + j * 16 + fro;
      float* op = out + (size_t)(n >> 10) * 524288 + (n & 1023);
#pragma unroll
      for (int g = 0; g < 4; ++g)
        op[(size_t)(crow + i * 16 + g) * 1024] = acc[i][j][g];
    }
#undef STG2
#undef RDF
}

// ---------------- generic bf16 GEMM, C = A(MxK) * B(NxK)^T, 128x128 tile ----
// EPI: 0 = fp32 + row/col bias (S), 1 = bf16 store, 2 = bf16 transposed store,
//      3 = fp32 store, 4 = bf16 store + chunk+512 = P0*v, 5 = bf16 store P0*v
template <int EPI>
__global__ __launch_bounds__(256) void gemm_bt(
    const u16* __restrict__ A, long long sA, int lda,
    const u16* __restrict__ B, long long sB, int ldb,
    void* __restrict__ Cv, long long sC, int ldc, int K,
    const float* __restrict__ brow, const float* __restrict__ bcol,
    int brs, int bcs, const u16* __restrict__ P0) {
  __shared__ u16 As[128 * 64];
  __shared__ u16 Bs[128 * 64];
  const int b = blockIdx.z;
  const int m0 = blockIdx.x * 128;
  const int n0 = blockIdx.y * 128;
  const u16* Ab = A + (size_t)b * sA;
  const u16* Bb = B + (size_t)b * sB;
  const int t = threadIdx.x;
  const int lane = t & 63;
  const int w = t >> 6;
  const int wr = w >> 1, wc = w & 1;
  const int srow = lane >> 3;
  const int scol = (lane & 7) * 8;

  f32x4 acc[4][4] = {};

  for (int k0 = 0; k0 < K; k0 += 64) {
    __syncthreads();
#pragma unroll
    for (int qq = 0; qq < 4; ++qq) {
      const int q = w * 4 + qq;
      const int r = q * 8 + srow;
      lds16(Ab + (size_t)(m0 + r) * lda + k0 + scol, &As[q * 512]);
      lds16(Bb + (size_t)(n0 + r) * ldb + k0 + scol, &Bs[q * 512]);
    }
    __syncthreads();
#pragma unroll
    for (int ks = 0; ks < 2; ++ks) {
      short8 af[4], bg[4];
      const int fro = lane & 15;
      const int k8 = ks * 32 + (lane >> 4) * 8;
#pragma unroll
      for (int i = 0; i < 4; ++i)
        af[i] = *(const short8*)&As[(wr * 64 + i * 16 + fro) * 64 + k8];
#pragma unroll
      for (int i = 0; i < 4; ++i)
        bg[i] = *(const short8*)&Bs[(wc * 64 + i * 16 + fro) * 64 + k8];
#pragma unroll
      for (int i = 0; i < 4; ++i)
#pragma unroll
        for (int j = 0; j < 4; ++j)
          acc[i][j] =
              __builtin_amdgcn_mfma_f32_16x16x32_bf16(af[i], bg[j], acc[i][j], 0, 0, 0);
    }
  }

  const int col = lane & 15;
  const int r4 = (lane >> 4) * 4;
#pragma unroll
  for (int i = 0; i < 4; ++i) {
#pragma unroll
    for (int j = 0; j < 4; ++j) {
      const int cc = n0 + wc * 64 + j * 16 + col;
#pragma unroll
      for (int g = 0; g < 4; ++g) {
        const int rr = m0 + wr * 64 + i * 16 + r4 + g;
        float v = acc[i][j][g];
        if (EPI == 0) {
          v += brow[b * brs + rr] + bcol[b * bcs + cc];
          ((float*)Cv)[(size_t)b * sC + (size_t)rr * ldc + cc] = v;
        } else if (EPI == 1) {
          ((u16*)Cv)[(size_t)b * sC + (size_t)rr * ldc + cc] = f2bf(v);
        } else if (EPI == 2) {
          ((u16*)Cv)[(size_t)b * sC + (size_t)cc * ldc + rr] = f2bf(v);
        } else if (EPI == 3) {
          ((float*)Cv)[(size_t)b * sC + (size_t)rr * ldc + cc] = v;
        } else if (EPI == 4) {
          const size_t off = (size_t)b * sC + (size_t)rr * ldc + cc;
          const float cf = bf2f(P0[off]);
          ((u16*)Cv)[off] = f2bf(v);
          ((u16*)Cv)[off + 512] = f2bf(cf * v);
        } else {
          const size_t off = (size_t)b * sC + (size_t)rr * ldc + cc;
          ((u16*)Cv)[off] = f2bf(bf2f(P0[off]) * v);
        }
      }
    }
  }
}

// ---- prep: C fp32 -> O chunk0 = C_t bf16 (ld 2048), Corig bf16, cbias atomic
__global__ __launch_bounds__(256) void prep_C(const float* __restrict__ C,
                                              const float* __restrict__ W0,
                                              u16* __restrict__ O,
                                              u16* __restrict__ Corig,
                                              float* __restrict__ cb) {
  __shared__ float L[64][65];
  __shared__ float P[4][64];
  const int b = blockIdx.z;
  const int d0 = blockIdx.y * 64;
  const int i0 = blockIdx.x * 64;
  const int t = threadIdx.x;
  const int cx = t & 63;
  const int rb = t >> 6;
  const float* Cb = C + ((size_t)b * 512 + d0) * 1024 + i0;
  float part = 0.f;
#pragma unroll
  for (int rr = 0; rr < 16; ++rr) {
    const int r = rb * 16 + rr;
    const float v = Cb[(size_t)r * 1024 + cx];
    L[r][cx] = v;
    part = fmaf(v, W0[d0 + r], part);
    Corig[((size_t)b * 512 + d0 + r) * 1024 + i0 + cx] = f2bf(v);
  }
  P[rb][cx] = part;
  __syncthreads();
#pragma unroll
  for (int rr = 0; rr < 16; ++rr) {
    const int il = rb * 16 + rr;
    O[((size_t)b * 1024 + i0 + il) * 2048 + d0 + cx] = f2bf(L[cx][il]);
  }
  if (rb == 0)
    atomicAdd(&cb[b * 1024 + i0 + cx], P[0][cx] + P[1][cx] + P[2][cx] + P[3][cx]);
}

// ---- prep: Q (B,512,128) -> Qmb = (Q_t * w_m) bf16 (128x512), Qorig bf16 ----
__global__ __launch_bounds__(256) void prep_Q(const float* __restrict__ Q,
                                              const float* __restrict__ W0,
                                              u16* __restrict__ Qmb,
                                              u16* __restrict__ Qorig) {
  __shared__ float L[64][65];
  const int b = blockIdx.z;
  const int d0 = blockIdx.y * 64;
  const int j0 = blockIdx.x * 64;
  const int t = threadIdx.x;
  const int cx = t & 63;
  const int rb = t >> 6;
  const float* Qb = Q + ((size_t)b * 512 + d0) * 128 + j0;
#pragma unroll
  for (int rr = 0; rr < 16; ++rr) {
    const int r = rb * 16 + rr;
    const float v = Qb[(size_t)r * 128 + cx];
    L[r][cx] = v;
    Qorig[((size_t)b * 512 + d0 + r) * 128 + j0 + cx] = f2bf(v);
  }
  __syncthreads();
  const float wm = W0[1024 + d0 + cx];
#pragma unroll
  for (int rr = 0; rr < 16; ++rr) {
    const int jl = rb * 16 + rr;
    Qmb[((size_t)b * 128 + j0 + jl) * 512 + d0 + cx] = f2bf(L[cx][jl] * wm);
  }
}

__global__ __launch_bounds__(128) void bias_q(const float* __restrict__ Q,
                                              const float* __restrict__ W0,
                                              float* __restrict__ qb) {
  const int b = blockIdx.x;
  const int j = threadIdx.x;
  const float* Qb = Q + (size_t)b * 65536;
  float a = 0.f;
  for (int d = 0; d < 512; ++d) a = fmaf(Qb[(size_t)d * 128 + j], W0[512 + d], a);
  qb[b * 128 + j] = a;
}

// ---- row softmax over j (width 128), one wave per row ----------------------
__global__ __launch_bounds__(256) void row_softmax(const float* __restrict__ S,
                                                   const float* __restrict__ qmask,
                                                   u16* __restrict__ Sbar) {
  const int t = threadIdx.x;
  const int lane = t & 63;
  const int row = blockIdx.x * 4 + (t >> 6);
  const int b = row >> 10;
  const float* Sr = S + (size_t)row * 128;
  const float* qmb = qmask + b * 128;
  const int j0 = lane * 2;
  const float q0 = qmb[j0], q1 = qmb[j0 + 1];
  const float x0 = Sr[j0] * q0 + NEGV * (1.f - q0);
  const float x1 = Sr[j0 + 1] * q1 + NEGV * (1.f - q1);
  float mx = fmaxf(x0, x1);
  for (int o = 32; o; o >>= 1) mx = fmaxf(mx, __shfl_xor(mx, o));
  const float e0 = expf(x0 - mx), e1 = expf(x1 - mx);
  float s = e0 + e1;
  for (int o = 32; o; o >>= 1) s += __shfl_xor(s, o);
  const float inv = 1.f / s;
  unsigned pack = (unsigned)f2bf(e0 * inv) | ((unsigned)f2bf(e1 * inv) << 16);
  *(unsigned*)(Sbar + (size_t)row * 128 + j0) = pack;
}

// ---- column stats (max, sumexp) per (b, j) ---------------------------------
__global__ __launch_bounds__(1024) void col_stats(const float* __restrict__ S,
                                                  const float* __restrict__ cmask,
                                                  float* __restrict__ cmx,
                                                  float* __restrict__ csm) {
  __shared__ float sm[8][128];
  __shared__ float sl[8][128];
  const int b = blockIdx.x;
  const int t = threadIdx.x;
  const int j = t & 127, g = t >> 7;
  const float* Sb = S + (size_t)b * 131072;
  const float* cm = cmask + b * 1024;
  float m = -3.4e38f;
  for (int ii = 0; ii < 128; ++ii) {
    const int i = g * 128 + ii;
    const float c = cm[i];
    m = fmaxf(m, Sb[(size_t)i * 128 + j] * c + NEGV * (1.f - c));
  }
  sm[g][j] = m;
  __syncthreads();
  if (g == 0) {
    float M = sm[0][j];
#pragma unroll
    for (int k = 1; k < 8; ++k) M = fmaxf(M, sm[k][j]);
    sm[0][j] = M;
  }
  __syncthreads();
  const float M = sm[0][j];
  float l = 0.f;
  for (int ii = 0; ii < 128; ++ii) {
    const int i = g * 128 + ii;
    const float c = cm[i];
    l += expf(Sb[(size_t)i * 128 + j] * c + NEGV * (1.f - c) - M);
  }
  sl[g][j] = l;
  __syncthreads();
  if (g == 0) {
    float L = 0.f;
#pragma unroll
    for (int k = 0; k < 8; ++k) L += sl[k][j];
    cmx[b * 128 + j] = M;
    csm[b * 128 + j] = L;
  }
}

// ---- S_bbar^T (B,128,1024) bf16, via LDS transpose -------------------------
__global__ __launch_bounds__(256) void sbbt_k(const float* __restrict__ S,
                                              const float* __restrict__ cmask,
                                              const float* __restrict__ cmx,
                                              const float* __restrict__ csm,
                                              u16* __restrict__ Sbbt) {
  __shared__ u16 L[128][130];
  const int b = blockIdx.y;
  const int i0 = blockIdx.x * 128;
  const int t = threadIdx.x;
  const int j = t & 127, ih = t >> 7;
  const float* Sb = S + (size_t)b * 131072;
  const float* cm = cmask + b * 1024;
  const float M = cmx[b * 128 + j];
  const float R = 1.f / csm[b * 128 + j];
  for (int ii = 0; ii < 64; ++ii) {
    const int il = ih * 64 + ii;
    const float c = cm[i0 + il];
    const float x = Sb[(size_t)(i0 + il) * 128 + j] * c + NEGV * (1.f - c);
    L[il][j] = f2bf(expf(x - M) * R);
  }
  __syncthreads();
  const int ip = t & 127, jb = t >> 7;
  for (int jj = 0; jj < 64; ++jj) {
    const int jl = jb * 64 + jj;
    Sbbt[((size_t)b * 128 + jl) * 1024 + i0 + ip] = L[ip][jl];
  }
}

// ---- Wr fp32 -> bf16 -------------------------------------------------------
__global__ __launch_bounds__(256) void cvt_wr(const float* __restrict__ Wr,
                                              u16* __restrict__ Wrb) {
  const int idx = blockIdx.x * 256 + threadIdx.x;
  const float4 v = ((const float4*)Wr)[idx];
  short4v o;
  o[0] = (short)f2bf(v.x);
  o[1] = (short)f2bf(v.y);
  o[2] = (short)f2bf(v.z);
  o[3] = (short)f2bf(v.w);
  *(short4v*)&Wrb[(size_t)idx * 4] = o;
}

extern "C" void kernel_launch(void* const* d_in, const int* in_sizes, int n_in,
                              void* d_out, int out_size, void* d_ws, size_t ws_size,
                              hipStream_t stream) {
  (void)in_sizes; (void)n_in; (void)out_size;
  const float* C = (const float*)d_in[0];
  const float* Q = (const float*)d_in[1];
  const float* cm = (const float*)d_in[2];
  const float* qm = (const float*)d_in[3];
  const float* W0 = (const float*)d_in[4];
  const float* Wr = (const float*)d_in[5];
  float* out = (float*)d_out;

  if (ws_size < 430276608ull) return;  // need ~410 MiB scratch

  char* p = (char*)d_ws;
  u16* O     = (u16*)(p);                    // (B,1024,2048) bf16: [C_t|A|C*A|C*Bm]
  u16* Corig = (u16*)(p + 268435456ull);     // (B,512,1024) bf16
  u16* Qmb   = (u16*)(p + 335544320ull);     // (B,128,512)  bf16  Q_t*w_m
  u16* Qorig = (u16*)(p + 343932928ull);     // (B,512,128)  bf16
  float* S   = (float*)(p + 352321536ull);   // (B,1024,128) fp32
  u16* Sbar  = (u16*)(p + 385875968ull);     // (B,1024,128) bf16
  u16* Sbbt  = (u16*)(p + 402653184ull);     // (B,128,1024) bf16
  u16* Tt    = (u16*)(p + 419430400ull);     // (B,512,128)  bf16  T^T
  u16* Wrb   = (u16*)(p + 427819008ull);     // (512,2048)   bf16
  float* cb  = (float*)(p + 429916160ull);   // (B,1024)
  float* qb  = (float*)(p + 430178304ull);   // (B,128)
  float* cmx = (float*)(p + 430211072ull);   // (B,128)
  float* csm = (float*)(p + 430243840ull);   // (B,128)

  hipFuncSetAttribute((const void*)gemm8,
                      hipFuncAttributeMaxDynamicSharedMemorySize, 131072);
  hipMemsetAsync(cb, 0, 262144, stream);

  cvt_wr<<<dim3(1024), dim3(256), 0, stream>>>(Wr, Wrb);
  prep_C<<<dim3(16, 8, 64), dim3(256), 0, stream>>>(C, W0, O, Corig, cb);
  prep_Q<<<dim3(2, 8, 64), dim3(256), 0, stream>>>(Q, W0, Qmb, Qorig);
  bias_q<<<dim3(64), dim3(128), 0, stream>>>(Q, W0, qb);

  // S = C_t @ (Q_t*w_m)^T + cbias + qbias   (M=1024,N=128,K=512)
  gemm_bt<0><<<dim3(8, 1, 64), dim3(256), 0, stream>>>(
      O, 2097152ll, 2048, Qmb, 65536ll, 512, S, 131072ll, 128, 512, cb, qb,
      1024, 128, nullptr);

  row_softmax<<<dim3(16384), dim3(256), 0, stream>>>(S, qm, Sbar);
  col_stats<<<dim3(64), dim3(1024), 0, stream>>>(S, cm, cmx, csm);
  sbbt_k<<<dim3(8, 64), dim3(256), 0, stream>>>(S, cm, cmx, csm, Sbbt);

  // A = Sbar @ Q_t -> O chunk1, and chunk2 = C_t*A (fused products)
  gemm_bt<4><<<dim3(8, 4, 64), dim3(256), 0, stream>>>(
      Sbar, 131072ll, 128, Qorig, 65536ll, 128, O + 512, 2097152ll, 2048, 128,
      nullptr, nullptr, 0, 0, O);
  // T^T: T = Sbbar^T @ C_t (M=128,N=512,K=1024), stored transposed (512x128)
  gemm_bt<2><<<dim3(1, 4, 64), dim3(256), 0, stream>>>(
      Sbbt, 131072ll, 1024, Corig, 524288ll, 1024, Tt, 65536ll, 128, 1024,
      nullptr, nullptr, 0, 0, nullptr);
  // Bm = Sbar @ T -> O chunk3 = C_t*Bm directly (fused products)
  gemm_bt<5><<<dim3(8, 4, 64), dim3(256), 0, stream>>>(
      Sbar, 131072ll, 128, Tt, 65536ll, 128, O + 1536, 2097152ll, 2048, 128,
      nullptr, nullptr, 0, 0, O);

  // R = Wr @ out^T : flattened M=512, N=65536, K=2048, 256^2 8-phase
  gemm8<<<dim3(512), dim3(512), 131072, stream>>>(Wrb, O, out);
}

// Round 3
// 457.613 us; speedup vs baseline: 1.3286x; 1.0568x over previous
//
#include <hip/hip_runtime.h>
#include <hip/hip_bf16.h>

typedef unsigned short u16;
typedef __attribute__((ext_vector_type(8))) short short8;
typedef __attribute__((ext_vector_type(4))) short short4v;
typedef __attribute__((ext_vector_type(4))) float f32x4;

#define NEGV -1000000000000000.0f
#define SBAR() asm volatile("s_barrier" ::: "memory")

__device__ __forceinline__ u16 f2bf(float f) {
  unsigned u = __float_as_uint(f);
  unsigned r = (u + 0x7FFFu + ((u >> 16) & 1u)) >> 16;
  return (u16)r;
}
__device__ __forceinline__ float bf2f(u16 s) {
  return __uint_as_float(((unsigned)s) << 16);
}
__device__ __forceinline__ void lds16(const void* g, void* l) {
  __builtin_amdgcn_global_load_lds((const __attribute__((address_space(1))) void*)g,
                                   (__attribute__((address_space(3))) void*)l,
                                   16, 0, 0);
}

// ============ 256x256 8-phase GEMM: out = Wrb(512x2048) @ Oflat(65536x2048)^T
// Revised staging: A (L2-resident Wrb) shallow t+1 at p0/p1; B (HBM stream)
// deep t+2 at p2/p3. Single counted vmcnt(2) per tile at p2. T2 swizzle,
// T5 setprio, raw s_barrier. 8 waves (2M x 4N), BK=64.
__global__ __launch_bounds__(512, 2) void gemm8(const u16* __restrict__ A,
                                                const u16* __restrict__ B,
                                                float* __restrict__ out) {
  extern __shared__ u16 lds[];  // 128 KiB: A dbuf 2x32KB | B dbuf 2x32KB
  const int bid = blockIdx.x;
  const int wg = (bid & 7) * 64 + (bid >> 3);  // m-pair shares B-tile on one XCD
  const int m0 = (wg & 1) * 256;
  const int n0 = (wg >> 1) * 256;
  const int tid = threadIdx.x;
  const int lane = tid & 63;
  const int w = tid >> 6;
  const int wr = w >> 2;
  const int wc = w & 3;
  const int fro = lane & 15;
  const int hi = lane >> 4;
  const int kx = fro & 7;
  const int sr = lane >> 3;
  const int sgc = ((lane & 7) ^ sr) << 3;  // pre-swizzled source column (elems)

  const u16* Ag = A + (size_t)m0 * 2048;
  const u16* Bg = B + (size_t)n0 * 2048;

  const int rA = wr * 128 + fro;
  const int rB = wc * 64 + fro;

  f32x4 acc[8][4] = {};
  short8 aX[4][2], aY[4][2], bP[2][2], bQ[2][2];

#define STG2(gp, lp)                                                          \
  {                                                                           \
    lds16((gp) + (size_t)((w * 2 + 0) * 8 + sr) * 2048 + sgc,                 \
          (u16*)(lp) + (w * 2 + 0) * 512);                                    \
    lds16((gp) + (size_t)((w * 2 + 1) * 8 + sr) * 2048 + sgc,                 \
          (u16*)(lp) + (w * 2 + 1) * 512);                                    \
  }
#define RDF(base, row, k16) \
  (*(const short8*)&(base)[(size_t)(row) * 64 + (((k16) ^ kx) << 3)])

  // ---- prologue: A(t0), B(t0), B(t1)
  STG2(Ag, lds);                        // A0 lo
  STG2(Ag + 262144, lds + 8192);        // A0 hi
  STG2(Bg, lds + 32768);                // B0 lo
  STG2(Bg + 262144, lds + 40960);       // B0 hi
  STG2(Bg + 64, lds + 49152);           // B1 lo
  STG2(Bg + 262144 + 64, lds + 57344);  // B1 hi
  asm volatile("s_waitcnt vmcnt(4)" ::: "memory");  // A0+B0 complete
  SBAR();
#pragma unroll
  for (int i = 0; i < 4; ++i)
#pragma unroll
    for (int ks = 0; ks < 2; ++ks) aX[i][ks] = RDF(lds, rA + i * 16, ks * 4 + hi);

  for (int t = 0; t < 32; ++t) {
    const int cur = t & 1;
    const int nxt = cur ^ 1;
    const u16* LA = lds + cur * 16384;
    const u16* LB = lds + 32768 + cur * 16384;
    u16* LAs = lds + nxt * 16384;          // stage A(t+1)
    u16* LBs = lds + 32768 + cur * 16384;  // stage B(t+2) (over B(t), read-done)
    const u16* LAn = lds + nxt * 16384;
    const int kkA = (t < 31 ? t + 1 : 31) * 64;
    const int kkB = (t < 30 ? t + 2 : 31) * 64;

    // ---- phase 0: read bP(t); stage A-low(t+1); mfma q0 = i0-3 x j0-1
#pragma unroll
    for (int j = 0; j < 2; ++j)
#pragma unroll
      for (int ks = 0; ks < 2; ++ks) bP[j][ks] = RDF(LB, rB + j * 16, ks * 4 + hi);
    STG2(Ag + kkA, LAs);
    SBAR();
    __builtin_amdgcn_s_setprio(1);
#pragma unroll
    for (int i = 0; i < 4; ++i)
#pragma unroll
      for (int j = 0; j < 2; ++j)
#pragma unroll
        for (int ks = 0; ks < 2; ++ks)
          acc[i][j] = __builtin_amdgcn_mfma_f32_16x16x32_bf16(aX[i][ks], bP[j][ks],
                                                              acc[i][j], 0, 0, 0);
    __builtin_amdgcn_s_setprio(0);
    SBAR();

    // ---- phase 1: read bQ(t), aY(t); stage A-high(t+1); mfma q1 = i0-3 x j2-3
#pragma unroll
    for (int j = 0; j < 2; ++j)
#pragma unroll
      for (int ks = 0; ks < 2; ++ks)
        bQ[j][ks] = RDF(LB, rB + (j + 2) * 16, ks * 4 + hi);
#pragma unroll
    for (int i = 0; i < 4; ++i)
#pragma unroll
      for (int ks = 0; ks < 2; ++ks)
        aY[i][ks] = RDF(LA, rA + (i + 4) * 16, ks * 4 + hi);
    STG2(Ag + 262144 + kkA, LAs + 8192);
    SBAR();
    __builtin_amdgcn_s_setprio(1);
#pragma unroll
    for (int i = 0; i < 4; ++i)
#pragma unroll
      for (int j = 0; j < 2; ++j)
#pragma unroll
        for (int ks = 0; ks < 2; ++ks)
          acc[i][j + 2] = __builtin_amdgcn_mfma_f32_16x16x32_bf16(
              aX[i][ks], bQ[j][ks], acc[i][j + 2], 0, 0, 0);
    __builtin_amdgcn_s_setprio(0);
    SBAR();

    // ---- phase 2: stage B-low(t+2); vmcnt(2) -> B(t+1)+A(t+1) done;
    //      mfma q2 = i4-7 x j2-3
    STG2(Bg + kkB, LBs);
    asm volatile("s_waitcnt vmcnt(2)" ::: "memory");
    SBAR();
    __builtin_amdgcn_s_setprio(1);
#pragma unroll
    for (int i = 0; i < 4; ++i)
#pragma unroll
      for (int j = 0; j < 2; ++j)
#pragma unroll
        for (int ks = 0; ks < 2; ++ks)
          acc[i + 4][j + 2] = __builtin_amdgcn_mfma_f32_16x16x32_bf16(
              aY[i][ks], bQ[j][ks], acc[i + 4][j + 2], 0, 0, 0);
    __builtin_amdgcn_s_setprio(0);
    SBAR();

    // ---- phase 3: read aX(t+1); stage B-high(t+2); mfma q3 = i4-7 x j0-1
#pragma unroll
    for (int i = 0; i < 4; ++i)
#pragma unroll
      for (int ks = 0; ks < 2; ++ks)
        aX[i][ks] = RDF(LAn, rA + i * 16, ks * 4 + hi);
    STG2(Bg + 262144 + kkB, LBs + 8192);
    SBAR();
    __builtin_amdgcn_s_setprio(1);
#pragma unroll
    for (int i = 0; i < 4; ++i)
#pragma unroll
      for (int j = 0; j < 2; ++j)
#pragma unroll
        for (int ks = 0; ks < 2; ++ks)
          acc[i + 4][j] = __builtin_amdgcn_mfma_f32_16x16x32_bf16(
              aY[i][ks], bP[j][ks], acc[i + 4][j], 0, 0, 0);
    __builtin_amdgcn_s_setprio(0);
    SBAR();
  }
  asm volatile("s_waitcnt vmcnt(0)" ::: "memory");

  // ---- epilogue: out[b][r][c], n = n0 + wc*64 + j*16 + fro
  const int crow = m0 + wr * 128 + hi * 4;
#pragma unroll
  for (int i = 0; i < 8; ++i)
#pragma unroll
    for (int j = 0; j < 4; ++j) {
      const int n = n0 + wc * 64 + j * 16 + fro;
      float* op = out + (size_t)(n >> 10) * 524288 + (n & 1023);
#pragma unroll
      for (int g = 0; g < 4; ++g)
        op[(size_t)(crow + i * 16 + g) * 1024] = acc[i][j][g];
    }
#undef STG2
#undef RDF
}

// ---------------- generic bf16 GEMM, C = A(MxK) * B(NxK)^T, 128x128 tile ----
// EPI: 2 = bf16 transposed store (used for T-GEMM)
template <int EPI>
__global__ __launch_bounds__(256) void gemm_bt(
    const u16* __restrict__ A, long long sA, int lda,
    const u16* __restrict__ B, long long sB, int ldb,
    void* __restrict__ Cv, long long sC, int ldc, int K) {
  __shared__ u16 As[128 * 64];
  __shared__ u16 Bs[128 * 64];
  const int b = blockIdx.z;
  const int m0 = blockIdx.x * 128;
  const int n0 = blockIdx.y * 128;
  const u16* Ab = A + (size_t)b * sA;
  const u16* Bb = B + (size_t)b * sB;
  const int t = threadIdx.x;
  const int lane = t & 63;
  const int w = t >> 6;
  const int wr = w >> 1, wc = w & 1;
  const int srow = lane >> 3;
  const int scol = (lane & 7) * 8;

  f32x4 acc[4][4] = {};

  for (int k0 = 0; k0 < K; k0 += 64) {
    __syncthreads();
#pragma unroll
    for (int qq = 0; qq < 4; ++qq) {
      const int q = w * 4 + qq;
      const int r = q * 8 + srow;
      lds16(Ab + (size_t)(m0 + r) * lda + k0 + scol, &As[q * 512]);
      lds16(Bb + (size_t)(n0 + r) * ldb + k0 + scol, &Bs[q * 512]);
    }
    __syncthreads();
#pragma unroll
    for (int ks = 0; ks < 2; ++ks) {
      short8 af[4], bg[4];
      const int fro = lane & 15;
      const int k8 = ks * 32 + (lane >> 4) * 8;
#pragma unroll
      for (int i = 0; i < 4; ++i)
        af[i] = *(const short8*)&As[(wr * 64 + i * 16 + fro) * 64 + k8];
#pragma unroll
      for (int i = 0; i < 4; ++i)
        bg[i] = *(const short8*)&Bs[(wc * 64 + i * 16 + fro) * 64 + k8];
#pragma unroll
      for (int i = 0; i < 4; ++i)
#pragma unroll
        for (int j = 0; j < 4; ++j)
          acc[i][j] =
              __builtin_amdgcn_mfma_f32_16x16x32_bf16(af[i], bg[j], acc[i][j], 0, 0, 0);
    }
  }

  const int col = lane & 15;
  const int r4 = (lane >> 4) * 4;
#pragma unroll
  for (int i = 0; i < 4; ++i)
#pragma unroll
    for (int j = 0; j < 4; ++j) {
      const int cc = n0 + wc * 64 + j * 16 + col;
#pragma unroll
      for (int g = 0; g < 4; ++g) {
        const int rr = m0 + wr * 64 + i * 16 + r4 + g;
        if (EPI == 2)
          ((u16*)Cv)[(size_t)b * sC + (size_t)cc * ldc + rr] = f2bf(acc[i][j][g]);
      }
    }
}

// ============ S-GEMM + fused dual softmax epilogue ==========================
// S = C_t @ Qmb^T + cb + qb  (M=1024, N=128=ALL j, K=512). Epilogue:
// row-softmax -> Sbar; col-path unnormalized exp -> E + atomic colsum.
__global__ __launch_bounds__(256) void gemm_s(
    const u16* __restrict__ A, const u16* __restrict__ Bq,
    const float* __restrict__ cb, const float* __restrict__ qb,
    const float* __restrict__ cmask, const float* __restrict__ qmask,
    u16* __restrict__ Sbar, u16* __restrict__ E, float* __restrict__ csum) {
  __shared__ u16 As[128 * 64];
  __shared__ u16 Bs[128 * 64];
  __shared__ float rmaxs[2][128];
  __shared__ float rsums[2][128];
  __shared__ float cparts[2][128];
  const int b = blockIdx.z;
  const int m0 = blockIdx.x * 128;
  const u16* Ab = A + (size_t)b * 2097152;
  const u16* Bb = Bq + (size_t)b * 65536;
  const int t = threadIdx.x;
  const int lane = t & 63;
  const int w = t >> 6;
  const int wr = w >> 1, wc = w & 1;
  const int srow = lane >> 3;
  const int scol = (lane & 7) * 8;

  f32x4 acc[4][4] = {};

  for (int k0 = 0; k0 < 512; k0 += 64) {
    __syncthreads();
#pragma unroll
    for (int qq = 0; qq < 4; ++qq) {
      const int q = w * 4 + qq;
      const int r = q * 8 + srow;
      lds16(Ab + (size_t)(m0 + r) * 2048 + k0 + scol, &As[q * 512]);
      lds16(Bb + (size_t)r * 512 + k0 + scol, &Bs[q * 512]);
    }
    __syncthreads();
#pragma unroll
    for (int ks = 0; ks < 2; ++ks) {
      short8 af[4], bg[4];
      const int fro = lane & 15;
      const int k8 = ks * 32 + (lane >> 4) * 8;
#pragma unroll
      for (int i = 0; i < 4; ++i)
        af[i] = *(const short8*)&As[(wr * 64 + i * 16 + fro) * 64 + k8];
#pragma unroll
      for (int i = 0; i < 4; ++i)
        bg[i] = *(const short8*)&Bs[(wc * 64 + i * 16 + fro) * 64 + k8];
#pragma unroll
      for (int i = 0; i < 4; ++i)
#pragma unroll
        for (int j = 0; j < 4; ++j)
          acc[i][j] =
              __builtin_amdgcn_mfma_f32_16x16x32_bf16(af[i], bg[j], acc[i][j], 0, 0, 0);
    }
  }

  const int fro = lane & 15;
  const int hi = lane >> 4;
  float qv[4], qbv[4];
#pragma unroll
  for (int j = 0; j < 4; ++j) {
    const int cc = wc * 64 + j * 16 + fro;
    qv[j] = qmask[b * 128 + cc];
    qbv[j] = qb[b * 128 + cc];
  }
  // pass 1: bias add in place; col-path exp, E store, col partials
  float colp[4] = {0.f, 0.f, 0.f, 0.f};
#pragma unroll
  for (int i = 0; i < 4; ++i)
#pragma unroll
    for (int g = 0; g < 4; ++g) {
      const int rl = wr * 64 + i * 16 + hi * 4 + g;
      const float rb = cb[b * 1024 + m0 + rl];
      const float cv = cmask[b * 1024 + m0 + rl];
      const float coff = NEGV * (1.f - cv);
#pragma unroll
      for (int j = 0; j < 4; ++j) {
        const float v = acc[i][j][g] + rb + qbv[j];
        acc[i][j][g] = v;
        const float e = __expf(v * cv + coff);
        E[((size_t)b * 1024 + m0 + rl) * 128 + wc * 64 + j * 16 + fro] = f2bf(e);
        colp[j] += e;
      }
    }
#pragma unroll
  for (int j = 0; j < 4; ++j) {
    colp[j] += __shfl_xor(colp[j], 16);
    colp[j] += __shfl_xor(colp[j], 32);
  }
  if (hi == 0)
#pragma unroll
    for (int j = 0; j < 4; ++j) cparts[wr][wc * 64 + j * 16 + fro] = colp[j];
  // row-path: mask in place + per-row max (wave-local)
  float rtmp[4][4];
#pragma unroll
  for (int i = 0; i < 4; ++i)
#pragma unroll
    for (int g = 0; g < 4; ++g) {
      float m = -3.4e38f;
#pragma unroll
      for (int j = 0; j < 4; ++j) {
        const float xm = acc[i][j][g] * qv[j] + NEGV * (1.f - qv[j]);
        acc[i][j][g] = xm;
        m = fmaxf(m, xm);
      }
#pragma unroll
      for (int o = 8; o; o >>= 1) m = fmaxf(m, __shfl_xor(m, o));
      rtmp[i][g] = m;
    }
  if (fro == 0)
#pragma unroll
    for (int i = 0; i < 4; ++i)
#pragma unroll
      for (int g = 0; g < 4; ++g)
        rmaxs[wc][wr * 64 + i * 16 + hi * 4 + g] = rtmp[i][g];
  __syncthreads();
  if (t < 128) atomicAdd(&csum[b * 128 + t], cparts[0][t] + cparts[1][t]);
#pragma unroll
  for (int i = 0; i < 4; ++i)
#pragma unroll
    for (int g = 0; g < 4; ++g) {
      const int rl = wr * 64 + i * 16 + hi * 4 + g;
      const float M = fmaxf(rmaxs[0][rl], rmaxs[1][rl]);
      float s = 0.f;
#pragma unroll
      for (int j = 0; j < 4; ++j) {
        const float p = __expf(acc[i][j][g] - M);
        acc[i][j][g] = p;
        s += p;
      }
#pragma unroll
      for (int o = 8; o; o >>= 1) s += __shfl_xor(s, o);
      rtmp[i][g] = s;
    }
  if (fro == 0)
#pragma unroll
    for (int i = 0; i < 4; ++i)
#pragma unroll
      for (int g = 0; g < 4; ++g)
        rsums[wc][wr * 64 + i * 16 + hi * 4 + g] = rtmp[i][g];
  __syncthreads();
#pragma unroll
  for (int i = 0; i < 4; ++i)
#pragma unroll
    for (int g = 0; g < 4; ++g) {
      const int rl = wr * 64 + i * 16 + hi * 4 + g;
      const float inv = 1.f / (rsums[0][rl] + rsums[1][rl]);
#pragma unroll
      for (int j = 0; j < 4; ++j)
        Sbar[((size_t)b * 1024 + m0 + rl) * 128 + wc * 64 + j * 16 + fro] =
            f2bf(acc[i][j][g] * inv);
    }
}

// ---- Sbbt[b][j][i] = E[b][i][j] / csum[b][j]  (LDS transpose) --------------
__global__ __launch_bounds__(256) void make_sbbt(const u16* __restrict__ E,
                                                 const float* __restrict__ csum,
                                                 u16* __restrict__ Sbbt) {
  __shared__ u16 L[128][130];
  __shared__ float inv[128];
  const int b = blockIdx.y;
  const int i0 = blockIdx.x * 128;
  const int t = threadIdx.x;
  if (t < 128) inv[t] = 1.f / csum[b * 128 + t];
  const int c = t & 127;
  const int r0 = t >> 7;
#pragma unroll
  for (int rr = 0; rr < 64; ++rr) {
    const int r = r0 * 64 + rr;
    L[r][c] = E[((size_t)b * 1024 + i0 + r) * 128 + c];
  }
  __syncthreads();
#pragma unroll
  for (int jj = 0; jj < 64; ++jj) {
    const int j = r0 * 64 + jj;
    Sbbt[((size_t)b * 128 + j) * 1024 + i0 + c] = f2bf(bf2f(L[c][j]) * inv[j]);
  }
}

// ============ merged A/Bm GEMM: Sbar @ {Qorig|Tt}, fused products ===========
__global__ __launch_bounds__(256) void gemm_ab(const u16* __restrict__ Sbar,
                                               const u16* __restrict__ Qo,
                                               const u16* __restrict__ Tt,
                                               u16* __restrict__ O) {
  __shared__ u16 As[128 * 64];
  __shared__ u16 Bs[128 * 64];
  const int b = blockIdx.z;
  const int m0 = blockIdx.x * 128;
  const int yy = blockIdx.y;
  const bool isA = yy < 4;
  const int dcol = (yy & 3) * 128;
  const u16* Ab = Sbar + (size_t)b * 131072;
  const u16* Bb = (isA ? Qo : Tt) + (size_t)b * 65536 + (size_t)dcol * 128;
  const int t = threadIdx.x;
  const int lane = t & 63;
  const int w = t >> 6;
  const int wr = w >> 1, wc = w & 1;
  const int srow = lane >> 3;
  const int scol = (lane & 7) * 8;

  f32x4 acc[4][4] = {};

  for (int k0 = 0; k0 < 128; k0 += 64) {
    __syncthreads();
#pragma unroll
    for (int qq = 0; qq < 4; ++qq) {
      const int q = w * 4 + qq;
      const int r = q * 8 + srow;
      lds16(Ab + (size_t)(m0 + r) * 128 + k0 + scol, &As[q * 512]);
      lds16(Bb + (size_t)r * 128 + k0 + scol, &Bs[q * 512]);
    }
    __syncthreads();
#pragma unroll
    for (int ks = 0; ks < 2; ++ks) {
      short8 af[4], bg[4];
      const int fro = lane & 15;
      const int k8 = ks * 32 + (lane >> 4) * 8;
#pragma unroll
      for (int i = 0; i < 4; ++i)
        af[i] = *(const short8*)&As[(wr * 64 + i * 16 + fro) * 64 + k8];
#pragma unroll
      for (int i = 0; i < 4; ++i)
        bg[i] = *(const short8*)&Bs[(wc * 64 + i * 16 + fro) * 64 + k8];
#pragma unroll
      for (int i = 0; i < 4; ++i)
#pragma unroll
        for (int j = 0; j < 4; ++j)
          acc[i][j] =
              __builtin_amdgcn_mfma_f32_16x16x32_bf16(af[i], bg[j], acc[i][j], 0, 0, 0);
    }
  }

  const int col = lane & 15;
  const int r4 = (lane >> 4) * 4;
#pragma unroll
  for (int i = 0; i < 4; ++i)
#pragma unroll
    for (int j = 0; j < 4; ++j) {
      const int cc = wc * 64 + j * 16 + col;
#pragma unroll
      for (int g = 0; g < 4; ++g) {
        const int rr = m0 + wr * 64 + i * 16 + r4 + g;
        const size_t obase = (size_t)b * 2097152 + (size_t)rr * 2048 + dcol + cc;
        const float v = acc[i][j][g];
        const float cf = bf2f(O[obase]);
        if (isA) {
          O[obase + 512] = f2bf(v);
          O[obase + 1024] = f2bf(cf * v);
        } else {
          O[obase + 1536] = f2bf(cf * v);
        }
      }
    }
}

// ---- prep: C fp32 -> O chunk0 = C_t bf16 (ld 2048), Corig bf16, cbias atomic
__global__ __launch_bounds__(256) void prep_C(const float* __restrict__ C,
                                              const float* __restrict__ W0,
                                              u16* __restrict__ O,
                                              u16* __restrict__ Corig,
                                              float* __restrict__ cb) {
  __shared__ float L[64][65];
  __shared__ float P[4][64];
  const int b = blockIdx.z;
  const int d0 = blockIdx.y * 64;
  const int i0 = blockIdx.x * 64;
  const int t = threadIdx.x;
  const int cx = t & 63;
  const int rb = t >> 6;
  const float* Cb = C + ((size_t)b * 512 + d0) * 1024 + i0;
  float part = 0.f;
#pragma unroll
  for (int rr = 0; rr < 16; ++rr) {
    const int r = rb * 16 + rr;
    const float v = Cb[(size_t)r * 1024 + cx];
    L[r][cx] = v;
    part = fmaf(v, W0[d0 + r], part);
    Corig[((size_t)b * 512 + d0 + r) * 1024 + i0 + cx] = f2bf(v);
  }
  P[rb][cx] = part;
  __syncthreads();
#pragma unroll
  for (int rr = 0; rr < 16; ++rr) {
    const int il = rb * 16 + rr;
    O[((size_t)b * 1024 + i0 + il) * 2048 + d0 + cx] = f2bf(L[cx][il]);
  }
  if (rb == 0)
    atomicAdd(&cb[b * 1024 + i0 + cx], P[0][cx] + P[1][cx] + P[2][cx] + P[3][cx]);
}

// ---- prep: Q -> Qmb = (Q_t * w_m) bf16, Qorig bf16, qbias atomic -----------
__global__ __launch_bounds__(256) void prep_Q(const float* __restrict__ Q,
                                              const float* __restrict__ W0,
                                              u16* __restrict__ Qmb,
                                              u16* __restrict__ Qorig,
                                              float* __restrict__ qb) {
  __shared__ float L[64][65];
  __shared__ float P[4][64];
  const int b = blockIdx.z;
  const int d0 = blockIdx.y * 64;
  const int j0 = blockIdx.x * 64;
  const int t = threadIdx.x;
  const int cx = t & 63;
  const int rb = t >> 6;
  const float* Qb = Q + ((size_t)b * 512 + d0) * 128 + j0;
  float part = 0.f;
#pragma unroll
  for (int rr = 0; rr < 16; ++rr) {
    const int r = rb * 16 + rr;
    const float v = Qb[(size_t)r * 128 + cx];
    L[r][cx] = v;
    part = fmaf(v, W0[512 + d0 + r], part);
    Qorig[((size_t)b * 512 + d0 + r) * 128 + j0 + cx] = f2bf(v);
  }
  P[rb][cx] = part;
  __syncthreads();
  const float wm = W0[1024 + d0 + cx];
#pragma unroll
  for (int rr = 0; rr < 16; ++rr) {
    const int jl = rb * 16 + rr;
    Qmb[((size_t)b * 128 + j0 + jl) * 512 + d0 + cx] = f2bf(L[cx][jl] * wm);
  }
  if (rb == 0)
    atomicAdd(&qb[b * 128 + j0 + cx], P[0][cx] + P[1][cx] + P[2][cx] + P[3][cx]);
}

// ---- Wr fp32 -> bf16 -------------------------------------------------------
__global__ __launch_bounds__(256) void cvt_wr(const float* __restrict__ Wr,
                                              u16* __restrict__ Wrb) {
  const int idx = blockIdx.x * 256 + threadIdx.x;
  const float4 v = ((const float4*)Wr)[idx];
  short4v o;
  o[0] = (short)f2bf(v.x);
  o[1] = (short)f2bf(v.y);
  o[2] = (short)f2bf(v.z);
  o[3] = (short)f2bf(v.w);
  *(short4v*)&Wrb[(size_t)idx * 4] = o;
}

extern "C" void kernel_launch(void* const* d_in, const int* in_sizes, int n_in,
                              void* d_out, int out_size, void* d_ws, size_t ws_size,
                              hipStream_t stream) {
  (void)in_sizes; (void)n_in; (void)out_size;
  const float* C = (const float*)d_in[0];
  const float* Q = (const float*)d_in[1];
  const float* cm = (const float*)d_in[2];
  const float* qm = (const float*)d_in[3];
  const float* W0 = (const float*)d_in[4];
  const float* Wr = (const float*)d_in[5];
  float* out = (float*)d_out;

  if (ws_size < 413466624ull) return;  // ~395 MiB scratch

  char* p = (char*)d_ws;
  u16* O     = (u16*)(p);                    // (B,1024,2048) bf16 [C_t|A|C*A|C*Bm]
  u16* Corig = (u16*)(p + 268435456ull);     // (B,512,1024) bf16
  u16* Qmb   = (u16*)(p + 335544320ull);     // (B,128,512)  bf16
  u16* Qorig = (u16*)(p + 343932928ull);     // (B,512,128)  bf16
  u16* E     = (u16*)(p + 352321536ull);     // (B,1024,128) bf16 unnorm col-exp
  u16* Sbar  = (u16*)(p + 369098752ull);     // (B,1024,128) bf16
  u16* Sbbt  = (u16*)(p + 385875968ull);     // (B,128,1024) bf16
  u16* Tt    = (u16*)(p + 402653184ull);     // (B,512,128)  bf16
  u16* Wrb   = (u16*)(p + 411041792ull);     // (512,2048)   bf16
  float* cb  = (float*)(p + 413138944ull);   // (B,1024)
  float* qb  = (float*)(p + 413401088ull);   // (B,128)
  float* csum= (float*)(p + 413433856ull);   // (B,128)

  hipFuncSetAttribute((const void*)gemm8,
                      hipFuncAttributeMaxDynamicSharedMemorySize, 131072);
  hipMemsetAsync(cb, 0, 327680, stream);  // cb + qb + csum contiguous

  cvt_wr<<<dim3(1024), dim3(256), 0, stream>>>(Wr, Wrb);
  prep_C<<<dim3(16, 8, 64), dim3(256), 0, stream>>>(C, W0, O, Corig, cb);
  prep_Q<<<dim3(2, 8, 64), dim3(256), 0, stream>>>(Q, W0, Qmb, Qorig, qb);

  // S-GEMM + fused row softmax + col-exp stats
  gemm_s<<<dim3(8, 1, 64), dim3(256), 0, stream>>>(O, Qmb, cb, qb, cm, qm,
                                                   Sbar, E, csum);
  make_sbbt<<<dim3(8, 64), dim3(256), 0, stream>>>(E, csum, Sbbt);

  // T^T: T = Sbbar^T @ C_t (M=128,N=512,K=1024), stored transposed (512x128)
  gemm_bt<2><<<dim3(1, 4, 64), dim3(256), 0, stream>>>(
      Sbbt, 131072ll, 1024, Corig, 524288ll, 1024, Tt, 65536ll, 128, 1024);

  // A & Bm merged (K=128): chunks 1,2,3 of O with fused C_t products
  gemm_ab<<<dim3(8, 8, 64), dim3(256), 0, stream>>>(Sbar, Qorig, Tt, O);

  // R = Wr @ out^T : flattened M=512, N=65536, K=2048, 256^2 8-phase
  gemm8<<<dim3(512), dim3(512), 131072, stream>>>(Wrb, O, out);
}

// Round 4
// 398.540 us; speedup vs baseline: 1.5255x; 1.1482x over previous
//
#include <hip/hip_runtime.h>
#include <hip/hip_bf16.h>

typedef unsigned short u16;
typedef __attribute__((ext_vector_type(8))) short short8;
typedef __attribute__((ext_vector_type(4))) short short4v;
typedef __attribute__((ext_vector_type(4))) float f32x4;

#define NEGV -1000000000000000.0f
#define SBAR() asm volatile("s_barrier" ::: "memory")

__device__ __forceinline__ u16 f2bf(float f) {
  unsigned u = __float_as_uint(f);
  unsigned r = (u + 0x7FFFu + ((u >> 16) & 1u)) >> 16;
  return (u16)r;
}
__device__ __forceinline__ float bf2f(u16 s) {
  return __uint_as_float(((unsigned)s) << 16);
}
__device__ __forceinline__ void lds16(const void* g, void* l) {
  __builtin_amdgcn_global_load_lds((const __attribute__((address_space(1))) void*)g,
                                   (__attribute__((address_space(3))) void*)l,
                                   16, 0, 0);
}

// ============ 256x256 8-phase GEMM: out = Wrb(512x2048) @ Oflat(65536x2048)^T
// A (L2-resident Wrb) shallow t+1 at p0/p1; B (HBM stream) deep t+2 at p2/p3.
// Single counted vmcnt(2) per tile at p2. T2 swizzle, T5 setprio, raw barrier.
__global__ __launch_bounds__(512, 2) void gemm8(const u16* __restrict__ A,
                                                const u16* __restrict__ B,
                                                float* __restrict__ out) {
  extern __shared__ u16 lds[];  // 128 KiB: A dbuf 2x32KB | B dbuf 2x32KB
  const int bid = blockIdx.x;
  const int wg = (bid & 7) * 64 + (bid >> 3);  // m-pair shares B-tile on one XCD
  const int m0 = (wg & 1) * 256;
  const int n0 = (wg >> 1) * 256;
  const int tid = threadIdx.x;
  const int lane = tid & 63;
  const int w = tid >> 6;
  const int wr = w >> 2;
  const int wc = w & 3;
  const int fro = lane & 15;
  const int hi = lane >> 4;
  const int kx = fro & 7;
  const int sr = lane >> 3;
  const int sgc = ((lane & 7) ^ sr) << 3;  // pre-swizzled source column (elems)

  const u16* Ag = A + (size_t)m0 * 2048;
  const u16* Bg = B + (size_t)n0 * 2048;

  const int rA = wr * 128 + fro;
  const int rB = wc * 64 + fro;

  f32x4 acc[8][4] = {};
  short8 aX[4][2], aY[4][2], bP[2][2], bQ[2][2];

#define STG2(gp, lp)                                                          \
  {                                                                           \
    lds16((gp) + (size_t)((w * 2 + 0) * 8 + sr) * 2048 + sgc,                 \
          (u16*)(lp) + (w * 2 + 0) * 512);                                    \
    lds16((gp) + (size_t)((w * 2 + 1) * 8 + sr) * 2048 + sgc,                 \
          (u16*)(lp) + (w * 2 + 1) * 512);                                    \
  }
#define RDF(base, row, k16) \
  (*(const short8*)&(base)[(size_t)(row) * 64 + (((k16) ^ kx) << 3)])

  // ---- prologue: A(t0), B(t0), B(t1)
  STG2(Ag, lds);                        // A0 lo
  STG2(Ag + 262144, lds + 8192);        // A0 hi
  STG2(Bg, lds + 32768);                // B0 lo
  STG2(Bg + 262144, lds + 40960);       // B0 hi
  STG2(Bg + 64, lds + 49152);           // B1 lo
  STG2(Bg + 262144 + 64, lds + 57344);  // B1 hi
  asm volatile("s_waitcnt vmcnt(4)" ::: "memory");  // A0+B0 complete
  SBAR();
#pragma unroll
  for (int i = 0; i < 4; ++i)
#pragma unroll
    for (int ks = 0; ks < 2; ++ks) aX[i][ks] = RDF(lds, rA + i * 16, ks * 4 + hi);

  for (int t = 0; t < 32; ++t) {
    const int cur = t & 1;
    const int nxt = cur ^ 1;
    const u16* LA = lds + cur * 16384;
    const u16* LB = lds + 32768 + cur * 16384;
    u16* LAs = lds + nxt * 16384;          // stage A(t+1)
    u16* LBs = lds + 32768 + cur * 16384;  // stage B(t+2) (over B(t), read-done)
    const u16* LAn = lds + nxt * 16384;
    const int kkA = (t < 31 ? t + 1 : 31) * 64;
    const int kkB = (t < 30 ? t + 2 : 31) * 64;

    // ---- phase 0: read bP(t); stage A-low(t+1); mfma q0 = i0-3 x j0-1
#pragma unroll
    for (int j = 0; j < 2; ++j)
#pragma unroll
      for (int ks = 0; ks < 2; ++ks) bP[j][ks] = RDF(LB, rB + j * 16, ks * 4 + hi);
    STG2(Ag + kkA, LAs);
    SBAR();
    __builtin_amdgcn_s_setprio(1);
#pragma unroll
    for (int i = 0; i < 4; ++i)
#pragma unroll
      for (int j = 0; j < 2; ++j)
#pragma unroll
        for (int ks = 0; ks < 2; ++ks)
          acc[i][j] = __builtin_amdgcn_mfma_f32_16x16x32_bf16(aX[i][ks], bP[j][ks],
                                                              acc[i][j], 0, 0, 0);
    __builtin_amdgcn_s_setprio(0);
    SBAR();

    // ---- phase 1: read bQ(t), aY(t); stage A-high(t+1); mfma q1 = i0-3 x j2-3
#pragma unroll
    for (int j = 0; j < 2; ++j)
#pragma unroll
      for (int ks = 0; ks < 2; ++ks)
        bQ[j][ks] = RDF(LB, rB + (j + 2) * 16, ks * 4 + hi);
#pragma unroll
    for (int i = 0; i < 4; ++i)
#pragma unroll
      for (int ks = 0; ks < 2; ++ks)
        aY[i][ks] = RDF(LA, rA + (i + 4) * 16, ks * 4 + hi);
    STG2(Ag + 262144 + kkA, LAs + 8192);
    SBAR();
    __builtin_amdgcn_s_setprio(1);
#pragma unroll
    for (int i = 0; i < 4; ++i)
#pragma unroll
      for (int j = 0; j < 2; ++j)
#pragma unroll
        for (int ks = 0; ks < 2; ++ks)
          acc[i][j + 2] = __builtin_amdgcn_mfma_f32_16x16x32_bf16(
              aX[i][ks], bQ[j][ks], acc[i][j + 2], 0, 0, 0);
    __builtin_amdgcn_s_setprio(0);
    SBAR();

    // ---- phase 2: stage B-low(t+2); vmcnt(2) -> B(t+1)+A(t+1) done;
    //      mfma q2 = i4-7 x j2-3
    STG2(Bg + kkB, LBs);
    asm volatile("s_waitcnt vmcnt(2)" ::: "memory");
    SBAR();
    __builtin_amdgcn_s_setprio(1);
#pragma unroll
    for (int i = 0; i < 4; ++i)
#pragma unroll
      for (int j = 0; j < 2; ++j)
#pragma unroll
        for (int ks = 0; ks < 2; ++ks)
          acc[i + 4][j + 2] = __builtin_amdgcn_mfma_f32_16x16x32_bf16(
              aY[i][ks], bQ[j][ks], acc[i + 4][j + 2], 0, 0, 0);
    __builtin_amdgcn_s_setprio(0);
    SBAR();

    // ---- phase 3: read aX(t+1); stage B-high(t+2); mfma q3 = i4-7 x j0-1
#pragma unroll
    for (int i = 0; i < 4; ++i)
#pragma unroll
      for (int ks = 0; ks < 2; ++ks)
        aX[i][ks] = RDF(LAn, rA + i * 16, ks * 4 + hi);
    STG2(Bg + 262144 + kkB, LBs + 8192);
    SBAR();
    __builtin_amdgcn_s_setprio(1);
#pragma unroll
    for (int i = 0; i < 4; ++i)
#pragma unroll
      for (int j = 0; j < 2; ++j)
#pragma unroll
        for (int ks = 0; ks < 2; ++ks)
          acc[i + 4][j] = __builtin_amdgcn_mfma_f32_16x16x32_bf16(
              aY[i][ks], bP[j][ks], acc[i + 4][j], 0, 0, 0);
    __builtin_amdgcn_s_setprio(0);
    SBAR();
  }
  asm volatile("s_waitcnt vmcnt(0)" ::: "memory");

  // ---- epilogue: out[b][r][c], n = n0 + wc*64 + j*16 + fro
  const int crow = m0 + wr * 128 + hi * 4;
#pragma unroll
  for (int i = 0; i < 8; ++i)
#pragma unroll
    for (int j = 0; j < 4; ++j) {
      const int n = n0 + wc * 64 + j * 16 + fro;
      float* op = out + (size_t)(n >> 10) * 524288 + (n & 1023);
#pragma unroll
      for (int g = 0; g < 4; ++g)
        op[(size_t)(crow + i * 16 + g) * 1024] = acc[i][j][g];
    }
#undef STG2
#undef RDF
}

// ---------------- generic bf16 GEMM, C = A(MxK) * B(NxK)^T, 128x128 tile ----
// EPI: 2 = bf16 transposed store (used for T-GEMM)
template <int EPI>
__global__ __launch_bounds__(256) void gemm_bt(
    const u16* __restrict__ A, long long sA, int lda,
    const u16* __restrict__ B, long long sB, int ldb,
    void* __restrict__ Cv, long long sC, int ldc, int K) {
  __shared__ u16 As[128 * 64];
  __shared__ u16 Bs[128 * 64];
  const int b = blockIdx.z;
  const int m0 = blockIdx.x * 128;
  const int n0 = blockIdx.y * 128;
  const u16* Ab = A + (size_t)b * sA;
  const u16* Bb = B + (size_t)b * sB;
  const int t = threadIdx.x;
  const int lane = t & 63;
  const int w = t >> 6;
  const int wr = w >> 1, wc = w & 1;
  const int srow = lane >> 3;
  const int scol = (lane & 7) * 8;

  f32x4 acc[4][4] = {};

  for (int k0 = 0; k0 < K; k0 += 64) {
    __syncthreads();
#pragma unroll
    for (int qq = 0; qq < 4; ++qq) {
      const int q = w * 4 + qq;
      const int r = q * 8 + srow;
      lds16(Ab + (size_t)(m0 + r) * lda + k0 + scol, &As[q * 512]);
      lds16(Bb + (size_t)(n0 + r) * ldb + k0 + scol, &Bs[q * 512]);
    }
    __syncthreads();
#pragma unroll
    for (int ks = 0; ks < 2; ++ks) {
      short8 af[4], bg[4];
      const int fro = lane & 15;
      const int k8 = ks * 32 + (lane >> 4) * 8;
#pragma unroll
      for (int i = 0; i < 4; ++i)
        af[i] = *(const short8*)&As[(wr * 64 + i * 16 + fro) * 64 + k8];
#pragma unroll
      for (int i = 0; i < 4; ++i)
        bg[i] = *(const short8*)&Bs[(wc * 64 + i * 16 + fro) * 64 + k8];
#pragma unroll
      for (int i = 0; i < 4; ++i)
#pragma unroll
        for (int j = 0; j < 4; ++j)
          acc[i][j] =
              __builtin_amdgcn_mfma_f32_16x16x32_bf16(af[i], bg[j], acc[i][j], 0, 0, 0);
    }
  }

  const int col = lane & 15;
  const int r4 = (lane >> 4) * 4;
#pragma unroll
  for (int i = 0; i < 4; ++i)
#pragma unroll
    for (int j = 0; j < 4; ++j) {
      const int cc = n0 + wc * 64 + j * 16 + col;
#pragma unroll
      for (int g = 0; g < 4; ++g) {
        const int rr = m0 + wr * 64 + i * 16 + r4 + g;
        if (EPI == 2)
          ((u16*)Cv)[(size_t)b * sC + (size_t)cc * ldc + rr] = f2bf(acc[i][j][g]);
      }
    }
}

// ============ S-GEMM + fused dual softmax epilogue ==========================
// S = C_t @ Qmb^T + cb + qb  (M=1024, N=128=ALL j, K=512). Epilogue:
// row-softmax -> Sbar; col-path unnormalized exp -> E + atomic colsum.
__global__ __launch_bounds__(256) void gemm_s(
    const u16* __restrict__ A, const u16* __restrict__ Bq,
    const float* __restrict__ cb, const float* __restrict__ qb,
    const float* __restrict__ cmask, const float* __restrict__ qmask,
    u16* __restrict__ Sbar, u16* __restrict__ E, float* __restrict__ csum) {
  __shared__ u16 As[128 * 64];
  __shared__ u16 Bs[128 * 64];
  __shared__ float rmaxs[2][128];
  __shared__ float rsums[2][128];
  __shared__ float cparts[2][128];
  const int b = blockIdx.z;
  const int m0 = blockIdx.x * 128;
  const u16* Ab = A + (size_t)b * 2097152;
  const u16* Bb = Bq + (size_t)b * 65536;
  const int t = threadIdx.x;
  const int lane = t & 63;
  const int w = t >> 6;
  const int wr = w >> 1, wc = w & 1;
  const int srow = lane >> 3;
  const int scol = (lane & 7) * 8;

  f32x4 acc[4][4] = {};

  for (int k0 = 0; k0 < 512; k0 += 64) {
    __syncthreads();
#pragma unroll
    for (int qq = 0; qq < 4; ++qq) {
      const int q = w * 4 + qq;
      const int r = q * 8 + srow;
      lds16(Ab + (size_t)(m0 + r) * 2048 + k0 + scol, &As[q * 512]);
      lds16(Bb + (size_t)r * 512 + k0 + scol, &Bs[q * 512]);
    }
    __syncthreads();
#pragma unroll
    for (int ks = 0; ks < 2; ++ks) {
      short8 af[4], bg[4];
      const int fro = lane & 15;
      const int k8 = ks * 32 + (lane >> 4) * 8;
#pragma unroll
      for (int i = 0; i < 4; ++i)
        af[i] = *(const short8*)&As[(wr * 64 + i * 16 + fro) * 64 + k8];
#pragma unroll
      for (int i = 0; i < 4; ++i)
        bg[i] = *(const short8*)&Bs[(wc * 64 + i * 16 + fro) * 64 + k8];
#pragma unroll
      for (int i = 0; i < 4; ++i)
#pragma unroll
        for (int j = 0; j < 4; ++j)
          acc[i][j] =
              __builtin_amdgcn_mfma_f32_16x16x32_bf16(af[i], bg[j], acc[i][j], 0, 0, 0);
    }
  }

  const int fro = lane & 15;
  const int hi = lane >> 4;
  float qv[4], qbv[4];
#pragma unroll
  for (int j = 0; j < 4; ++j) {
    const int cc = wc * 64 + j * 16 + fro;
    qv[j] = qmask[b * 128 + cc];
    qbv[j] = qb[b * 128 + cc];
  }
  // pass 1: bias add in place; col-path exp, E store, col partials
  float colp[4] = {0.f, 0.f, 0.f, 0.f};
#pragma unroll
  for (int i = 0; i < 4; ++i)
#pragma unroll
    for (int g = 0; g < 4; ++g) {
      const int rl = wr * 64 + i * 16 + hi * 4 + g;
      const float rb = cb[b * 1024 + m0 + rl];
      const float cv = cmask[b * 1024 + m0 + rl];
      const float coff = NEGV * (1.f - cv);
#pragma unroll
      for (int j = 0; j < 4; ++j) {
        const float v = acc[i][j][g] + rb + qbv[j];
        acc[i][j][g] = v;
        const float e = __expf(v * cv + coff);
        E[((size_t)b * 1024 + m0 + rl) * 128 + wc * 64 + j * 16 + fro] = f2bf(e);
        colp[j] += e;
      }
    }
#pragma unroll
  for (int j = 0; j < 4; ++j) {
    colp[j] += __shfl_xor(colp[j], 16);
    colp[j] += __shfl_xor(colp[j], 32);
  }
  if (hi == 0)
#pragma unroll
    for (int j = 0; j < 4; ++j) cparts[wr][wc * 64 + j * 16 + fro] = colp[j];
  // row-path: mask in place + per-row max (wave-local)
  float rtmp[4][4];
#pragma unroll
  for (int i = 0; i < 4; ++i)
#pragma unroll
    for (int g = 0; g < 4; ++g) {
      float m = -3.4e38f;
#pragma unroll
      for (int j = 0; j < 4; ++j) {
        const float xm = acc[i][j][g] * qv[j] + NEGV * (1.f - qv[j]);
        acc[i][j][g] = xm;
        m = fmaxf(m, xm);
      }
#pragma unroll
      for (int o = 8; o; o >>= 1) m = fmaxf(m, __shfl_xor(m, o));
      rtmp[i][g] = m;
    }
  if (fro == 0)
#pragma unroll
    for (int i = 0; i < 4; ++i)
#pragma unroll
      for (int g = 0; g < 4; ++g)
        rmaxs[wc][wr * 64 + i * 16 + hi * 4 + g] = rtmp[i][g];
  __syncthreads();
  if (t < 128) atomicAdd(&csum[b * 128 + t], cparts[0][t] + cparts[1][t]);
#pragma unroll
  for (int i = 0; i < 4; ++i)
#pragma unroll
    for (int g = 0; g < 4; ++g) {
      const int rl = wr * 64 + i * 16 + hi * 4 + g;
      const float M = fmaxf(rmaxs[0][rl], rmaxs[1][rl]);
      float s = 0.f;
#pragma unroll
      for (int j = 0; j < 4; ++j) {
        const float p = __expf(acc[i][j][g] - M);
        acc[i][j][g] = p;
        s += p;
      }
#pragma unroll
      for (int o = 8; o; o >>= 1) s += __shfl_xor(s, o);
      rtmp[i][g] = s;
    }
  if (fro == 0)
#pragma unroll
    for (int i = 0; i < 4; ++i)
#pragma unroll
      for (int g = 0; g < 4; ++g)
        rsums[wc][wr * 64 + i * 16 + hi * 4 + g] = rtmp[i][g];
  __syncthreads();
#pragma unroll
  for (int i = 0; i < 4; ++i)
#pragma unroll
    for (int g = 0; g < 4; ++g) {
      const int rl = wr * 64 + i * 16 + hi * 4 + g;
      const float inv = 1.f / (rsums[0][rl] + rsums[1][rl]);
#pragma unroll
      for (int j = 0; j < 4; ++j)
        Sbar[((size_t)b * 1024 + m0 + rl) * 128 + wc * 64 + j * 16 + fro] =
            f2bf(acc[i][j][g] * inv);
    }
}

// ---- Sbbt[b][j][i] = E[b][i][j] / csum[b][j]  (LDS transpose) --------------
__global__ __launch_bounds__(256) void make_sbbt(const u16* __restrict__ E,
                                                 const float* __restrict__ csum,
                                                 u16* __restrict__ Sbbt) {
  __shared__ u16 L[128][130];
  __shared__ float inv[128];
  const int b = blockIdx.y;
  const int i0 = blockIdx.x * 128;
  const int t = threadIdx.x;
  if (t < 128) inv[t] = 1.f / csum[b * 128 + t];
  const int c = t & 127;
  const int r0 = t >> 7;
#pragma unroll
  for (int rr = 0; rr < 64; ++rr) {
    const int r = r0 * 64 + rr;
    L[r][c] = E[((size_t)b * 1024 + i0 + r) * 128 + c];
  }
  __syncthreads();
#pragma unroll
  for (int jj = 0; jj < 64; ++jj) {
    const int j = r0 * 64 + jj;
    Sbbt[((size_t)b * 128 + j) * 1024 + i0 + c] = f2bf(bf2f(L[c][j]) * inv[j]);
  }
}

// ============ merged A+Bm GEMM (shared A=Sbar), vectorized LDS epilogue =====
// Per block: m0 (128 rows of c), dcol (128 of d). acc_a = Sbar@Qo^T,
// acc_b = Sbar@Tt^T. Epilogue: chunk1 = A, chunk2 = C*A, chunk3 = C*Bm,
// all via LDS re-layout -> short8 (16B) stores.
__global__ __launch_bounds__(256) void gemm_ab(const u16* __restrict__ Sbar,
                                               const u16* __restrict__ Qo,
                                               const u16* __restrict__ Tt,
                                               u16* __restrict__ O) {
  __shared__ u16 sh[3 * 128 * 64];  // As | Bq | Bt ; first 32KB reused as Ls
  u16* As = sh;
  u16* Bq = sh + 8192;
  u16* Bt = sh + 16384;
  const int b = blockIdx.z;
  const int m0 = blockIdx.x * 128;
  const int dcol = blockIdx.y * 128;
  const u16* Ab = Sbar + (size_t)b * 131072;
  const u16* Qg = Qo + (size_t)b * 65536 + (size_t)dcol * 128;
  const u16* Tg = Tt + (size_t)b * 65536 + (size_t)dcol * 128;
  const int t = threadIdx.x;
  const int lane = t & 63;
  const int w = t >> 6;
  const int wr = w >> 1, wc = w & 1;
  const int srow = lane >> 3;
  const int scol = (lane & 7) * 8;
  const int fro = lane & 15;
  const int hi = lane >> 4;

  f32x4 aa[4][4] = {};
  f32x4 ab[4][4] = {};

  for (int k0 = 0; k0 < 128; k0 += 64) {
    __syncthreads();
#pragma unroll
    for (int qq = 0; qq < 4; ++qq) {
      const int q = w * 4 + qq;
      const int r = q * 8 + srow;
      lds16(Ab + (size_t)(m0 + r) * 128 + k0 + scol, &As[q * 512]);
      lds16(Qg + (size_t)r * 128 + k0 + scol, &Bq[q * 512]);
      lds16(Tg + (size_t)r * 128 + k0 + scol, &Bt[q * 512]);
    }
    __syncthreads();
#pragma unroll
    for (int ks = 0; ks < 2; ++ks) {
      short8 af[4], bq[4], bt[4];
      const int k8 = ks * 32 + hi * 8;
#pragma unroll
      for (int i = 0; i < 4; ++i) {
        af[i] = *(const short8*)&As[(wr * 64 + i * 16 + fro) * 64 + k8];
        bq[i] = *(const short8*)&Bq[(wc * 64 + i * 16 + fro) * 64 + k8];
        bt[i] = *(const short8*)&Bt[(wc * 64 + i * 16 + fro) * 64 + k8];
      }
#pragma unroll
      for (int i = 0; i < 4; ++i)
#pragma unroll
        for (int j = 0; j < 4; ++j) {
          aa[i][j] =
              __builtin_amdgcn_mfma_f32_16x16x32_bf16(af[i], bq[j], aa[i][j], 0, 0, 0);
          ab[i][j] =
              __builtin_amdgcn_mfma_f32_16x16x32_bf16(af[i], bt[j], ab[i][j], 0, 0, 0);
        }
    }
  }

  // ---- vectorized epilogue through LDS (Ls = 128x128 u16 = 32KB over As|Bq)
  u16* Ls = sh;
  const int erow = t >> 4;           // 0..15
  const int ecol = (t & 15) * 8;     // 0..120
  const size_t obase0 =
      (size_t)b * 2097152 + (size_t)m0 * 2048 + dcol;  // chunk0 + tile origin
  short8 c8[8];

  __syncthreads();
  // pass A: stage acc_a, emit chunk1 (A) + chunk2 (C*A), cache chunk0 in c8
#pragma unroll
  for (int i = 0; i < 4; ++i)
#pragma unroll
    for (int j = 0; j < 4; ++j)
#pragma unroll
      for (int g = 0; g < 4; ++g)
        Ls[(wr * 64 + i * 16 + hi * 4 + g) * 128 + wc * 64 + j * 16 + fro] =
            f2bf(aa[i][j][g]);
  __syncthreads();
#pragma unroll
  for (int it = 0; it < 8; ++it) {
    const int row = it * 16 + erow;
    const short8 a8 = *(const short8*)&Ls[row * 128 + ecol];
    c8[it] = *(const short8*)&O[obase0 + (size_t)row * 2048 + ecol];
    short8 p2;
#pragma unroll
    for (int k = 0; k < 8; ++k)
      p2[k] = (short)f2bf(bf2f((u16)c8[it][k]) * bf2f((u16)a8[k]));
    *(short8*)&O[obase0 + (size_t)row * 2048 + ecol + 512] = a8;
    *(short8*)&O[obase0 + (size_t)row * 2048 + ecol + 1024] = p2;
  }
  __syncthreads();
  // pass B: stage acc_b, emit chunk3 (C*Bm)
#pragma unroll
  for (int i = 0; i < 4; ++i)
#pragma unroll
    for (int j = 0; j < 4; ++j)
#pragma unroll
      for (int g = 0; g < 4; ++g)
        Ls[(wr * 64 + i * 16 + hi * 4 + g) * 128 + wc * 64 + j * 16 + fro] =
            f2bf(ab[i][j][g]);
  __syncthreads();
#pragma unroll
  for (int it = 0; it < 8; ++it) {
    const int row = it * 16 + erow;
    const short8 b8 = *(const short8*)&Ls[row * 128 + ecol];
    short8 p3;
#pragma unroll
    for (int k = 0; k < 8; ++k)
      p3[k] = (short)f2bf(bf2f((u16)c8[it][k]) * bf2f((u16)b8[k]));
    *(short8*)&O[obase0 + (size_t)row * 2048 + ecol + 1536] = p3;
  }
}

// ---- prep: C fp32 -> O chunk0 = C_t bf16 (ld 2048), Corig bf16, cbias atomic
__global__ __launch_bounds__(256) void prep_C(const float* __restrict__ C,
                                              const float* __restrict__ W0,
                                              u16* __restrict__ O,
                                              u16* __restrict__ Corig,
                                              float* __restrict__ cb) {
  __shared__ float L[64][65];
  __shared__ float P[4][64];
  const int b = blockIdx.z;
  const int d0 = blockIdx.y * 64;
  const int i0 = blockIdx.x * 64;
  const int t = threadIdx.x;
  const int cx = t & 63;
  const int rb = t >> 6;
  const float* Cb = C + ((size_t)b * 512 + d0) * 1024 + i0;
  float part = 0.f;
#pragma unroll
  for (int rr = 0; rr < 16; ++rr) {
    const int r = rb * 16 + rr;
    const float v = Cb[(size_t)r * 1024 + cx];
    L[r][cx] = v;
    part = fmaf(v, W0[d0 + r], part);
    Corig[((size_t)b * 512 + d0 + r) * 1024 + i0 + cx] = f2bf(v);
  }
  P[rb][cx] = part;
  __syncthreads();
#pragma unroll
  for (int rr = 0; rr < 16; ++rr) {
    const int il = rb * 16 + rr;
    O[((size_t)b * 1024 + i0 + il) * 2048 + d0 + cx] = f2bf(L[cx][il]);
  }
  if (rb == 0)
    atomicAdd(&cb[b * 1024 + i0 + cx], P[0][cx] + P[1][cx] + P[2][cx] + P[3][cx]);
}

// ---- prep: Q -> Qmb = (Q_t * w_m) bf16, Qorig bf16, qbias atomic -----------
__global__ __launch_bounds__(256) void prep_Q(const float* __restrict__ Q,
                                              const float* __restrict__ W0,
                                              u16* __restrict__ Qmb,
                                              u16* __restrict__ Qorig,
                                              float* __restrict__ qb) {
  __shared__ float L[64][65];
  __shared__ float P[4][64];
  const int b = blockIdx.z;
  const int d0 = blockIdx.y * 64;
  const int j0 = blockIdx.x * 64;
  const int t = threadIdx.x;
  const int cx = t & 63;
  const int rb = t >> 6;
  const float* Qb = Q + ((size_t)b * 512 + d0) * 128 + j0;
  float part = 0.f;
#pragma unroll
  for (int rr = 0; rr < 16; ++rr) {
    const int r = rb * 16 + rr;
    const float v = Qb[(size_t)r * 128 + cx];
    L[r][cx] = v;
    part = fmaf(v, W0[512 + d0 + r], part);
    Qorig[((size_t)b * 512 + d0 + r) * 128 + j0 + cx] = f2bf(v);
  }
  P[rb][cx] = part;
  __syncthreads();
  const float wm = W0[1024 + d0 + cx];
#pragma unroll
  for (int rr = 0; rr < 16; ++rr) {
    const int jl = rb * 16 + rr;
    Qmb[((size_t)b * 128 + j0 + jl) * 512 + d0 + cx] = f2bf(L[cx][jl] * wm);
  }
  if (rb == 0)
    atomicAdd(&qb[b * 128 + j0 + cx], P[0][cx] + P[1][cx] + P[2][cx] + P[3][cx]);
}

// ---- Wr fp32 -> bf16 -------------------------------------------------------
__global__ __launch_bounds__(256) void cvt_wr(const float* __restrict__ Wr,
                                              u16* __restrict__ Wrb) {
  const int idx = blockIdx.x * 256 + threadIdx.x;
  const float4 v = ((const float4*)Wr)[idx];
  short4v o;
  o[0] = (short)f2bf(v.x);
  o[1] = (short)f2bf(v.y);
  o[2] = (short)f2bf(v.z);
  o[3] = (short)f2bf(v.w);
  *(short4v*)&Wrb[(size_t)idx * 4] = o;
}

extern "C" void kernel_launch(void* const* d_in, const int* in_sizes, int n_in,
                              void* d_out, int out_size, void* d_ws, size_t ws_size,
                              hipStream_t stream) {
  (void)in_sizes; (void)n_in; (void)out_size;
  const float* C = (const float*)d_in[0];
  const float* Q = (const float*)d_in[1];
  const float* cm = (const float*)d_in[2];
  const float* qm = (const float*)d_in[3];
  const float* W0 = (const float*)d_in[4];
  const float* Wr = (const float*)d_in[5];
  float* out = (float*)d_out;

  if (ws_size < 413466624ull) return;  // ~395 MiB scratch

  char* p = (char*)d_ws;
  u16* O     = (u16*)(p);                    // (B,1024,2048) bf16 [C_t|A|C*A|C*Bm]
  u16* Corig = (u16*)(p + 268435456ull);     // (B,512,1024) bf16
  u16* Qmb   = (u16*)(p + 335544320ull);     // (B,128,512)  bf16
  u16* Qorig = (u16*)(p + 343932928ull);     // (B,512,128)  bf16
  u16* E     = (u16*)(p + 352321536ull);     // (B,1024,128) bf16 unnorm col-exp
  u16* Sbar  = (u16*)(p + 369098752ull);     // (B,1024,128) bf16
  u16* Sbbt  = (u16*)(p + 385875968ull);     // (B,128,1024) bf16
  u16* Tt    = (u16*)(p + 402653184ull);     // (B,512,128)  bf16
  u16* Wrb   = (u16*)(p + 411041792ull);     // (512,2048)   bf16
  float* cb  = (float*)(p + 413138944ull);   // (B,1024)
  float* qb  = (float*)(p + 413401088ull);   // (B,128)
  float* csum= (float*)(p + 413433856ull);   // (B,128)

  hipFuncSetAttribute((const void*)gemm8,
                      hipFuncAttributeMaxDynamicSharedMemorySize, 131072);
  hipMemsetAsync(cb, 0, 327680, stream);  // cb + qb + csum contiguous

  cvt_wr<<<dim3(1024), dim3(256), 0, stream>>>(Wr, Wrb);
  prep_C<<<dim3(16, 8, 64), dim3(256), 0, stream>>>(C, W0, O, Corig, cb);
  prep_Q<<<dim3(2, 8, 64), dim3(256), 0, stream>>>(Q, W0, Qmb, Qorig, qb);

  // S-GEMM + fused row softmax + col-exp stats
  gemm_s<<<dim3(8, 1, 64), dim3(256), 0, stream>>>(O, Qmb, cb, qb, cm, qm,
                                                   Sbar, E, csum);
  make_sbbt<<<dim3(8, 64), dim3(256), 0, stream>>>(E, csum, Sbbt);

  // T^T: T = Sbbar^T @ C_t (M=128,N=512,K=1024), stored transposed (512x128)
  gemm_bt<2><<<dim3(1, 4, 64), dim3(256), 0, stream>>>(
      Sbbt, 131072ll, 1024, Corig, 524288ll, 1024, Tt, 65536ll, 128, 1024);

  // A & Bm in one kernel (K=128): chunks 1,2,3 of O with fused C_t products
  gemm_ab<<<dim3(8, 4, 64), dim3(256), 0, stream>>>(Sbar, Qorig, Tt, O);

  // R = Wr @ out^T : flattened M=512, N=65536, K=2048, 256^2 8-phase
  gemm8<<<dim3(512), dim3(512), 131072, stream>>>(Wrb, O, out);
}

// Round 5
// 368.365 us; speedup vs baseline: 1.6505x; 1.0819x over previous
//
#include <hip/hip_runtime.h>
#include <hip/hip_bf16.h>

typedef unsigned short u16;
typedef __attribute__((ext_vector_type(8))) short short8;
typedef __attribute__((ext_vector_type(4))) short short4v;
typedef __attribute__((ext_vector_type(4))) float f32x4;

#define NEGV -1000000000000000.0f
#define SBAR() asm volatile("s_barrier" ::: "memory")

__device__ __forceinline__ u16 f2bf(float f) {
  unsigned u = __float_as_uint(f);
  unsigned r = (u + 0x7FFFu + ((u >> 16) & 1u)) >> 16;
  return (u16)r;
}
__device__ __forceinline__ float bf2f(u16 s) {
  return __uint_as_float(((unsigned)s) << 16);
}
__device__ __forceinline__ void lds16(const void* g, void* l) {
  __builtin_amdgcn_global_load_lds((const __attribute__((address_space(1))) void*)g,
                                   (__attribute__((address_space(3))) void*)l,
                                   16, 0, 0);
}

// ============ 256x256 GEMM, 16 waves (4Mx4N, 64x64/wave): out = Wrb @ O^T ===
// acc 64 regs/wave -> launch_bounds(1024) targets <=128 regs = 4 waves/SIMD.
// LDS 160KB: A dbuf 2x32K + B 3-buf 3x32K. 2 phases/K-tile; stage A(t+1)@p0,
// B(t+2)@p1; uniform vmcnt(2)@p1. T2 swizzle, T5 setprio, raw barriers.
__global__ __launch_bounds__(1024) void gemm8b(const u16* __restrict__ A,
                                               const u16* __restrict__ B,
                                               float* __restrict__ out) {
  extern __shared__ u16 lds[];
  const int bid = blockIdx.x;
  const int wg = (bid & 7) * 64 + (bid >> 3);  // m-pair shares B-tile on one XCD
  const int m0 = (wg & 1) * 256;
  const int n0 = (wg >> 1) * 256;
  const int tid = threadIdx.x;
  const int lane = tid & 63;
  const int w = tid >> 6;   // 0..15
  const int wr = w >> 2;    // 64-row band
  const int wc = w & 3;     // 64-col band
  const int fro = lane & 15;
  const int hi = lane >> 4;
  const int kx = fro & 7;
  const int sr = lane >> 3;
  const int sgc = ((lane & 7) ^ sr) << 3;  // pre-swizzled source col (elems)

  const u16* Ag = A + (size_t)m0 * 2048;
  const u16* Bg = B + (size_t)n0 * 2048;
  const int rA = wr * 64 + fro;
  const int rB = wc * 64 + fro;

  f32x4 acc[4][4] = {};

// one half-tile (128 rows x 64 cols) per call: 1024 thr x 16B
#define STG(gp, lp) \
  lds16((gp) + (size_t)(w * 8 + sr) * 2048 + sgc, (u16*)(lp) + w * 512)
#define RDF(base, row, k16) \
  (*(const short8*)&(base)[(size_t)(row) * 64 + (((k16) ^ kx) << 3)])

  // prologue: A0, B0, B1
  STG(Ag, lds);
  STG(Ag + 262144, lds + 8192);
  STG(Bg, lds + 32768);
  STG(Bg + 262144, lds + 32768 + 8192);
  STG(Bg + 64, lds + 49152);
  STG(Bg + 262144 + 64, lds + 49152 + 8192);
  asm volatile("s_waitcnt vmcnt(2)" ::: "memory");  // A0,B0 done; B1 in flight
  SBAR();

  const u16* Ac = lds;
  u16* An = lds + 16384;
  const u16* Bc = lds + 32768;   // B(t)
  const u16* Bn = lds + 49152;   // B(t+1)
  u16* Bs2 = lds + 65536;        // stage target B(t+2)

  for (int t = 0; t < 32; ++t) {
    const int kkA = (t < 31 ? t + 1 : 31) * 64;
    const int kkB = (t < 30 ? t + 2 : 31) * 64;
    short8 af[4], bf[4];

    // ---- phase 0 (ks=0): 8 ds_read; stage A(t+1); 16 MFMA
#pragma unroll
    for (int i = 0; i < 4; ++i) af[i] = RDF(Ac, rA + i * 16, hi);
#pragma unroll
    for (int j = 0; j < 4; ++j) bf[j] = RDF(Bc, rB + j * 16, hi);
    STG(Ag + kkA, An);
    STG(Ag + 262144 + kkA, An + 8192);
    SBAR();
    __builtin_amdgcn_s_setprio(1);
#pragma unroll
    for (int i = 0; i < 4; ++i)
#pragma unroll
      for (int j = 0; j < 4; ++j)
        acc[i][j] =
            __builtin_amdgcn_mfma_f32_16x16x32_bf16(af[i], bf[j], acc[i][j], 0, 0, 0);
    __builtin_amdgcn_s_setprio(0);
    SBAR();

    // ---- phase 1 (ks=1): 8 ds_read; stage B(t+2); vmcnt(2); 16 MFMA
#pragma unroll
    for (int i = 0; i < 4; ++i) af[i] = RDF(Ac, rA + i * 16, 4 + hi);
#pragma unroll
    for (int j = 0; j < 4; ++j) bf[j] = RDF(Bc, rB + j * 16, 4 + hi);
    STG(Bg + kkB, Bs2);
    STG(Bg + 262144 + kkB, Bs2 + 8192);
    asm volatile("s_waitcnt vmcnt(2)" ::: "memory");  // drain B(t+1), A(t+1)
    SBAR();
    __builtin_amdgcn_s_setprio(1);
#pragma unroll
    for (int i = 0; i < 4; ++i)
#pragma unroll
      for (int j = 0; j < 4; ++j)
        acc[i][j] =
            __builtin_amdgcn_mfma_f32_16x16x32_bf16(af[i], bf[j], acc[i][j], 0, 0, 0);
    __builtin_amdgcn_s_setprio(0);
    SBAR();

    // rotate buffers
    u16* tA = An; An = (u16*)Ac; Ac = tA;
    u16* tB = (u16*)Bc; Bc = Bn; Bn = Bs2; Bs2 = tB;
  }
  asm volatile("s_waitcnt vmcnt(0)" ::: "memory");

  // ---- epilogue: out[b][r][c], n = n0 + wc*64 + j*16 + fro
  const int crow = m0 + wr * 64 + hi * 4;
#pragma unroll
  for (int i = 0; i < 4; ++i)
#pragma unroll
    for (int j = 0; j < 4; ++j) {
      const int n = n0 + wc * 64 + j * 16 + fro;
      float* op = out + (size_t)(n >> 10) * 524288 + (n & 1023);
#pragma unroll
      for (int g = 0; g < 4; ++g)
        op[(size_t)(crow + i * 16 + g) * 1024] = acc[i][j][g];
    }
#undef STG
#undef RDF
}

// ============ T-GEMM: C_un = EunT(128x1024) @ Corig(512x1024)^T, then
// Tt[b][d][j] = C_un[j][d] / csum[b][j]  (transposed scaled store) ===========
__global__ __launch_bounds__(256) void gemm_t(const u16* __restrict__ A,
                                              const u16* __restrict__ B,
                                              const float* __restrict__ csum,
                                              u16* __restrict__ Tt) {
  __shared__ u16 As[128 * 64];
  __shared__ u16 Bs[128 * 64];
  const int b = blockIdx.z;
  const int n0 = blockIdx.y * 128;
  const u16* Ab = A + (size_t)b * 131072;
  const u16* Bb = B + (size_t)b * 524288;
  const int t = threadIdx.x;
  const int lane = t & 63;
  const int w = t >> 6;
  const int wr = w >> 1, wc = w & 1;
  const int srow = lane >> 3;
  const int scol = (lane & 7) * 8;

  f32x4 acc[4][4] = {};

  for (int k0 = 0; k0 < 1024; k0 += 64) {
    __syncthreads();
#pragma unroll
    for (int qq = 0; qq < 4; ++qq) {
      const int q = w * 4 + qq;
      const int r = q * 8 + srow;
      lds16(Ab + (size_t)r * 1024 + k0 + scol, &As[q * 512]);
      lds16(Bb + (size_t)(n0 + r) * 1024 + k0 + scol, &Bs[q * 512]);
    }
    __syncthreads();
#pragma unroll
    for (int ks = 0; ks < 2; ++ks) {
      short8 af[4], bg[4];
      const int fro = lane & 15;
      const int k8 = ks * 32 + (lane >> 4) * 8;
#pragma unroll
      for (int i = 0; i < 4; ++i)
        af[i] = *(const short8*)&As[(wr * 64 + i * 16 + fro) * 64 + k8];
#pragma unroll
      for (int i = 0; i < 4; ++i)
        bg[i] = *(const short8*)&Bs[(wc * 64 + i * 16 + fro) * 64 + k8];
#pragma unroll
      for (int i = 0; i < 4; ++i)
#pragma unroll
        for (int j = 0; j < 4; ++j)
          acc[i][j] =
              __builtin_amdgcn_mfma_f32_16x16x32_bf16(af[i], bg[j], acc[i][j], 0, 0, 0);
    }
  }

  const int col = lane & 15;
  const int r4 = (lane >> 4) * 4;
#pragma unroll
  for (int i = 0; i < 4; ++i)
#pragma unroll
    for (int g = 0; g < 4; ++g) {
      const int rr = wr * 64 + i * 16 + r4 + g;  // j index
      const float inv = 1.f / csum[b * 128 + rr];
#pragma unroll
      for (int j = 0; j < 4; ++j) {
        const int cc = n0 + wc * 64 + j * 16 + col;  // d index
        Tt[(size_t)b * 65536 + (size_t)cc * 128 + rr] = f2bf(acc[i][j][g] * inv);
      }
    }
}

// ============ S-GEMM + fused dual softmax + transposed-Eun epilogue =========
// S = C_t @ Qmb^T + cb + qb (M=1024,N=128,K=512). Row-softmax -> Sbar;
// col-path unnormalized exp -> EunT (transposed) + atomic colsum.
__global__ __launch_bounds__(256) void gemm_s(
    const u16* __restrict__ A, const u16* __restrict__ Bq,
    const float* __restrict__ cb, const float* __restrict__ qb,
    const float* __restrict__ cmask, const float* __restrict__ qmask,
    u16* __restrict__ Sbar, u16* __restrict__ EunT, float* __restrict__ csum) {
  __shared__ u16 As[128 * 64];
  __shared__ u16 Bs[128 * 64];
  __shared__ u16 Lt[128][136];
  __shared__ float rmaxs[2][128];
  __shared__ float rsums[2][128];
  __shared__ float cparts[2][128];
  const int b = blockIdx.z;
  const int m0 = blockIdx.x * 128;
  const u16* Ab = A + (size_t)b * 2097152;
  const u16* Bb = Bq + (size_t)b * 65536;
  const int t = threadIdx.x;
  const int lane = t & 63;
  const int w = t >> 6;
  const int wr = w >> 1, wc = w & 1;
  const int srow = lane >> 3;
  const int scol = (lane & 7) * 8;

  f32x4 acc[4][4] = {};

  for (int k0 = 0; k0 < 512; k0 += 64) {
    __syncthreads();
#pragma unroll
    for (int qq = 0; qq < 4; ++qq) {
      const int q = w * 4 + qq;
      const int r = q * 8 + srow;
      lds16(Ab + (size_t)(m0 + r) * 2048 + k0 + scol, &As[q * 512]);
      lds16(Bb + (size_t)r * 512 + k0 + scol, &Bs[q * 512]);
    }
    __syncthreads();
#pragma unroll
    for (int ks = 0; ks < 2; ++ks) {
      short8 af[4], bg[4];
      const int fro = lane & 15;
      const int k8 = ks * 32 + (lane >> 4) * 8;
#pragma unroll
      for (int i = 0; i < 4; ++i)
        af[i] = *(const short8*)&As[(wr * 64 + i * 16 + fro) * 64 + k8];
#pragma unroll
      for (int i = 0; i < 4; ++i)
        bg[i] = *(const short8*)&Bs[(wc * 64 + i * 16 + fro) * 64 + k8];
#pragma unroll
      for (int i = 0; i < 4; ++i)
#pragma unroll
        for (int j = 0; j < 4; ++j)
          acc[i][j] =
              __builtin_amdgcn_mfma_f32_16x16x32_bf16(af[i], bg[j], acc[i][j], 0, 0, 0);
    }
  }

  const int fro = lane & 15;
  const int hi = lane >> 4;
  float qv[4], qbv[4];
#pragma unroll
  for (int j = 0; j < 4; ++j) {
    const int cc = wc * 64 + j * 16 + fro;
    qv[j] = qmask[b * 128 + cc];
    qbv[j] = qb[b * 128 + cc];
  }
  // pass 1: bias add; col-path exp -> Lt (transposed) + col partials
  float colp[4] = {0.f, 0.f, 0.f, 0.f};
#pragma unroll
  for (int i = 0; i < 4; ++i)
#pragma unroll
    for (int g = 0; g < 4; ++g) {
      const int rl = wr * 64 + i * 16 + hi * 4 + g;
      const float rb = cb[b * 1024 + m0 + rl];
      const float cv = cmask[b * 1024 + m0 + rl];
      const float coff = NEGV * (1.f - cv);
#pragma unroll
      for (int j = 0; j < 4; ++j) {
        const float v = acc[i][j][g] + rb + qbv[j];
        acc[i][j][g] = v;
        const float e = __expf(v * cv + coff);
        Lt[wc * 64 + j * 16 + fro][rl] = f2bf(e);
        colp[j] += e;
      }
    }
#pragma unroll
  for (int j = 0; j < 4; ++j) {
    colp[j] += __shfl_xor(colp[j], 16);
    colp[j] += __shfl_xor(colp[j], 32);
  }
  if (hi == 0)
#pragma unroll
    for (int j = 0; j < 4; ++j) cparts[wr][wc * 64 + j * 16 + fro] = colp[j];
  // row-path: mask + per-row max
  float rtmp[4][4];
#pragma unroll
  for (int i = 0; i < 4; ++i)
#pragma unroll
    for (int g = 0; g < 4; ++g) {
      float m = -3.4e38f;
#pragma unroll
      for (int j = 0; j < 4; ++j) {
        const float xm = acc[i][j][g] * qv[j] + NEGV * (1.f - qv[j]);
        acc[i][j][g] = xm;
        m = fmaxf(m, xm);
      }
#pragma unroll
      for (int o = 8; o; o >>= 1) m = fmaxf(m, __shfl_xor(m, o));
      rtmp[i][g] = m;
    }
  if (fro == 0)
#pragma unroll
    for (int i = 0; i < 4; ++i)
#pragma unroll
      for (int g = 0; g < 4; ++g)
        rmaxs[wc][wr * 64 + i * 16 + hi * 4 + g] = rtmp[i][g];
  __syncthreads();  // Lt, rmaxs, cparts visible
  if (t < 128) atomicAdd(&csum[b * 128 + t], cparts[0][t] + cparts[1][t]);
  // EunT transpose-out: thread t -> row j = t>>1, i-half = (t&1)*64
  {
    const int jr = t >> 1;
    const int ih = (t & 1) * 64;
    u16* dst = EunT + (size_t)b * 131072 + (size_t)jr * 1024 + m0 + ih;
#pragma unroll
    for (int s = 0; s < 8; ++s)
      *(short8*)(dst + s * 8) = *(const short8*)&Lt[jr][ih + s * 8];
  }
  // row-path: exp + sum
#pragma unroll
  for (int i = 0; i < 4; ++i)
#pragma unroll
    for (int g = 0; g < 4; ++g) {
      const int rl = wr * 64 + i * 16 + hi * 4 + g;
      const float M = fmaxf(rmaxs[0][rl], rmaxs[1][rl]);
      float s = 0.f;
#pragma unroll
      for (int j = 0; j < 4; ++j) {
        const float p = __expf(acc[i][j][g] - M);
        acc[i][j][g] = p;
        s += p;
      }
#pragma unroll
      for (int o = 8; o; o >>= 1) s += __shfl_xor(s, o);
      rtmp[i][g] = s;
    }
  if (fro == 0)
#pragma unroll
    for (int i = 0; i < 4; ++i)
#pragma unroll
      for (int g = 0; g < 4; ++g)
        rsums[wc][wr * 64 + i * 16 + hi * 4 + g] = rtmp[i][g];
  __syncthreads();
#pragma unroll
  for (int i = 0; i < 4; ++i)
#pragma unroll
    for (int g = 0; g < 4; ++g) {
      const int rl = wr * 64 + i * 16 + hi * 4 + g;
      const float inv = 1.f / (rsums[0][rl] + rsums[1][rl]);
#pragma unroll
      for (int j = 0; j < 4; ++j)
        Sbar[((size_t)b * 1024 + m0 + rl) * 128 + wc * 64 + j * 16 + fro] =
            f2bf(acc[i][j][g] * inv);
    }
}

// ============ merged A+Bm GEMM (shared A=Sbar), vectorized LDS epilogue =====
__global__ __launch_bounds__(256) void gemm_ab(const u16* __restrict__ Sbar,
                                               const u16* __restrict__ Qo,
                                               const u16* __restrict__ Tt,
                                               u16* __restrict__ O) {
  __shared__ u16 sh[3 * 128 * 64];
  u16* As = sh;
  u16* Bq = sh + 8192;
  u16* Bt = sh + 16384;
  const int b = blockIdx.z;
  const int m0 = blockIdx.x * 128;
  const int dcol = blockIdx.y * 128;
  const u16* Ab = Sbar + (size_t)b * 131072;
  const u16* Qg = Qo + (size_t)b * 65536 + (size_t)dcol * 128;
  const u16* Tg = Tt + (size_t)b * 65536 + (size_t)dcol * 128;
  const int t = threadIdx.x;
  const int lane = t & 63;
  const int w = t >> 6;
  const int wr = w >> 1, wc = w & 1;
  const int srow = lane >> 3;
  const int scol = (lane & 7) * 8;
  const int fro = lane & 15;
  const int hi = lane >> 4;

  f32x4 aa[4][4] = {};
  f32x4 ab[4][4] = {};

  for (int k0 = 0; k0 < 128; k0 += 64) {
    __syncthreads();
#pragma unroll
    for (int qq = 0; qq < 4; ++qq) {
      const int q = w * 4 + qq;
      const int r = q * 8 + srow;
      lds16(Ab + (size_t)(m0 + r) * 128 + k0 + scol, &As[q * 512]);
      lds16(Qg + (size_t)r * 128 + k0 + scol, &Bq[q * 512]);
      lds16(Tg + (size_t)r * 128 + k0 + scol, &Bt[q * 512]);
    }
    __syncthreads();
#pragma unroll
    for (int ks = 0; ks < 2; ++ks) {
      short8 af[4], bq[4], bt[4];
      const int k8 = ks * 32 + hi * 8;
#pragma unroll
      for (int i = 0; i < 4; ++i) {
        af[i] = *(const short8*)&As[(wr * 64 + i * 16 + fro) * 64 + k8];
        bq[i] = *(const short8*)&Bq[(wc * 64 + i * 16 + fro) * 64 + k8];
        bt[i] = *(const short8*)&Bt[(wc * 64 + i * 16 + fro) * 64 + k8];
      }
#pragma unroll
      for (int i = 0; i < 4; ++i)
#pragma unroll
        for (int j = 0; j < 4; ++j) {
          aa[i][j] =
              __builtin_amdgcn_mfma_f32_16x16x32_bf16(af[i], bq[j], aa[i][j], 0, 0, 0);
          ab[i][j] =
              __builtin_amdgcn_mfma_f32_16x16x32_bf16(af[i], bt[j], ab[i][j], 0, 0, 0);
        }
    }
  }

  u16* Ls = sh;
  const int erow = t >> 4;
  const int ecol = (t & 15) * 8;
  const size_t obase0 = (size_t)b * 2097152 + (size_t)m0 * 2048 + dcol;
  short8 c8[8];

  __syncthreads();
#pragma unroll
  for (int i = 0; i < 4; ++i)
#pragma unroll
    for (int j = 0; j < 4; ++j)
#pragma unroll
      for (int g = 0; g < 4; ++g)
        Ls[(wr * 64 + i * 16 + hi * 4 + g) * 128 + wc * 64 + j * 16 + fro] =
            f2bf(aa[i][j][g]);
  __syncthreads();
#pragma unroll
  for (int it = 0; it < 8; ++it) {
    const int row = it * 16 + erow;
    const short8 a8 = *(const short8*)&Ls[row * 128 + ecol];
    c8[it] = *(const short8*)&O[obase0 + (size_t)row * 2048 + ecol];
    short8 p2;
#pragma unroll
    for (int k = 0; k < 8; ++k)
      p2[k] = (short)f2bf(bf2f((u16)c8[it][k]) * bf2f((u16)a8[k]));
    *(short8*)&O[obase0 + (size_t)row * 2048 + ecol + 512] = a8;
    *(short8*)&O[obase0 + (size_t)row * 2048 + ecol + 1024] = p2;
  }
  __syncthreads();
#pragma unroll
  for (int i = 0; i < 4; ++i)
#pragma unroll
    for (int j = 0; j < 4; ++j)
#pragma unroll
      for (int g = 0; g < 4; ++g)
        Ls[(wr * 64 + i * 16 + hi * 4 + g) * 128 + wc * 64 + j * 16 + fro] =
            f2bf(ab[i][j][g]);
  __syncthreads();
#pragma unroll
  for (int it = 0; it < 8; ++it) {
    const int row = it * 16 + erow;
    const short8 b8 = *(const short8*)&Ls[row * 128 + ecol];
    short8 p3;
#pragma unroll
    for (int k = 0; k < 8; ++k)
      p3[k] = (short)f2bf(bf2f((u16)c8[it][k]) * bf2f((u16)b8[k]));
    *(short8*)&O[obase0 + (size_t)row * 2048 + ecol + 1536] = p3;
  }
}

// ---- prep: C fp32 -> O chunk0 = C_t bf16 (ld 2048), Corig bf16, cbias atomic
__global__ __launch_bounds__(256) void prep_C(const float* __restrict__ C,
                                              const float* __restrict__ W0,
                                              u16* __restrict__ O,
                                              u16* __restrict__ Corig,
                                              float* __restrict__ cb) {
  __shared__ float L[64][65];
  __shared__ float P[4][64];
  const int b = blockIdx.z;
  const int d0 = blockIdx.y * 64;
  const int i0 = blockIdx.x * 64;
  const int t = threadIdx.x;
  const int cx = t & 63;
  const int rb = t >> 6;
  const float* Cb = C + ((size_t)b * 512 + d0) * 1024 + i0;
  float part = 0.f;
#pragma unroll
  for (int rr = 0; rr < 16; ++rr) {
    const int r = rb * 16 + rr;
    const float v = Cb[(size_t)r * 1024 + cx];
    L[r][cx] = v;
    part = fmaf(v, W0[d0 + r], part);
    Corig[((size_t)b * 512 + d0 + r) * 1024 + i0 + cx] = f2bf(v);
  }
  P[rb][cx] = part;
  __syncthreads();
#pragma unroll
  for (int rr = 0; rr < 16; ++rr) {
    const int il = rb * 16 + rr;
    O[((size_t)b * 1024 + i0 + il) * 2048 + d0 + cx] = f2bf(L[cx][il]);
  }
  if (rb == 0)
    atomicAdd(&cb[b * 1024 + i0 + cx], P[0][cx] + P[1][cx] + P[2][cx] + P[3][cx]);
}

// ---- prep: Q -> Qmb = (Q_t * w_m) bf16, Qorig bf16, qbias atomic -----------
__global__ __launch_bounds__(256) void prep_Q(const float* __restrict__ Q,
                                              const float* __restrict__ W0,
                                              u16* __restrict__ Qmb,
                                              u16* __restrict__ Qorig,
                                              float* __restrict__ qb) {
  __shared__ float L[64][65];
  __shared__ float P[4][64];
  const int b = blockIdx.z;
  const int d0 = blockIdx.y * 64;
  const int j0 = blockIdx.x * 64;
  const int t = threadIdx.x;
  const int cx = t & 63;
  const int rb = t >> 6;
  const float* Qb = Q + ((size_t)b * 512 + d0) * 128 + j0;
  float part = 0.f;
#pragma unroll
  for (int rr = 0; rr < 16; ++rr) {
    const int r = rb * 16 + rr;
    const float v = Qb[(size_t)r * 128 + cx];
    L[r][cx] = v;
    part = fmaf(v, W0[512 + d0 + r], part);
    Qorig[((size_t)b * 512 + d0 + r) * 128 + j0 + cx] = f2bf(v);
  }
  P[rb][cx] = part;
  __syncthreads();
  const float wm = W0[1024 + d0 + cx];
#pragma unroll
  for (int rr = 0; rr < 16; ++rr) {
    const int jl = rb * 16 + rr;
    Qmb[((size_t)b * 128 + j0 + jl) * 512 + d0 + cx] = f2bf(L[cx][jl] * wm);
  }
  if (rb == 0)
    atomicAdd(&qb[b * 128 + j0 + cx], P[0][cx] + P[1][cx] + P[2][cx] + P[3][cx]);
}

// ---- Wr fp32 -> bf16 -------------------------------------------------------
__global__ __launch_bounds__(256) void cvt_wr(const float* __restrict__ Wr,
                                              u16* __restrict__ Wrb) {
  const int idx = blockIdx.x * 256 + threadIdx.x;
  const float4 v = ((const float4*)Wr)[idx];
  short4v o;
  o[0] = (short)f2bf(v.x);
  o[1] = (short)f2bf(v.y);
  o[2] = (short)f2bf(v.z);
  o[3] = (short)f2bf(v.w);
  *(short4v*)&Wrb[(size_t)idx * 4] = o;
}

extern "C" void kernel_launch(void* const* d_in, const int* in_sizes, int n_in,
                              void* d_out, int out_size, void* d_ws, size_t ws_size,
                              hipStream_t stream) {
  (void)in_sizes; (void)n_in; (void)out_size;
  const float* C = (const float*)d_in[0];
  const float* Q = (const float*)d_in[1];
  const float* cm = (const float*)d_in[2];
  const float* qm = (const float*)d_in[3];
  const float* W0 = (const float*)d_in[4];
  const float* Wr = (const float*)d_in[5];
  float* out = (float*)d_out;

  if (ws_size < 405078016ull) return;  // ~386 MiB scratch

  char* p = (char*)d_ws;
  u16* O     = (u16*)(p);                    // (B,1024,2048) bf16 [C_t|A|C*A|C*Bm]
  u16* Corig = (u16*)(p + 268435456ull);     // (B,512,1024) bf16
  u16* Qmb   = (u16*)(p + 335544320ull);     // (B,128,512)  bf16
  u16* Qorig = (u16*)(p + 343932928ull);     // (B,512,128)  bf16
  u16* EunT  = (u16*)(p + 360710144ull);     // (B,128,1024) bf16 unnorm col-exp^T
  u16* Sbar  = (u16*)(p + 377487360ull);     // (B,1024,128) bf16
  u16* Tt    = (u16*)(p + 394264576ull);     // (B,512,128)  bf16
  u16* Wrb   = (u16*)(p + 402653184ull);     // (512,2048)   bf16
  float* cb  = (float*)(p + 404750336ull);   // (B,1024)
  float* qb  = (float*)(p + 405012480ull);   // (B,128)
  float* csum= (float*)(p + 405045248ull);   // (B,128)

  hipFuncSetAttribute((const void*)gemm8b,
                      hipFuncAttributeMaxDynamicSharedMemorySize, 163840);
  hipMemsetAsync(cb, 0, 327680, stream);  // cb + qb + csum contiguous

  cvt_wr<<<dim3(1024), dim3(256), 0, stream>>>(Wr, Wrb);
  prep_C<<<dim3(16, 8, 64), dim3(256), 0, stream>>>(C, W0, O, Corig, cb);
  prep_Q<<<dim3(2, 8, 64), dim3(256), 0, stream>>>(Q, W0, Qmb, Qorig, qb);

  // S-GEMM + fused row softmax + transposed unnormalized col-exp
  gemm_s<<<dim3(8, 1, 64), dim3(256), 0, stream>>>(O, Qmb, cb, qb, cm, qm,
                                                   Sbar, EunT, csum);

  // T^T scaled: Tt[b][d][j] = (EunT @ Corig^T)[j][d] / csum[b][j]
  gemm_t<<<dim3(1, 4, 64), dim3(256), 0, stream>>>(EunT, Corig, csum, Tt);

  // A & Bm in one kernel (K=128): chunks 1,2,3 of O with fused C_t products
  gemm_ab<<<dim3(8, 4, 64), dim3(256), 0, stream>>>(Sbar, Qorig, Tt, O);

  // R = Wr @ out^T : flattened M=512, N=65536, K=2048, 16-wave 256^2
  gemm8b<<<dim3(512), dim3(1024), 163840, stream>>>(Wrb, O, out);
}